// Round 7
// baseline (979.416 us; speedup 1.0000x reference)
//
#include <hip/hip_runtime.h>
#include <math.h>

typedef unsigned short u16;
typedef unsigned int   u32;
typedef unsigned long long u64;

#define NATOMS 8192
#define GRAPHS 64
#define APG    128
#define KNN    32
#define NGAUSS 50
#define HID    128
#define LAYERS 6
#define PAD128 136
#define MAXSLOTS 16384

typedef __attribute__((ext_vector_type(8))) short bf16x8;
typedef __attribute__((ext_vector_type(4))) float f32x4;

__device__ __forceinline__ float bf2f(u16 v) {
    return __uint_as_float(((u32)v) << 16);
}
__device__ __forceinline__ u16 f2bf(float f) {
    u32 u = __float_as_uint(f);
    u32 lsb = (u >> 16) & 1u;
    u += 0x7fffu + lsb;
    return (u16)(u >> 16);
}
__device__ __forceinline__ u32 pkbf(float lo, float hi) {
#if __has_builtin(__builtin_amdgcn_cvt_pk_bf16_f32)
    auto r = __builtin_amdgcn_cvt_pk_bf16_f32(lo, hi);
    u32 u; __builtin_memcpy(&u, &r, 4); return u;
#else
    return (u32)f2bf(lo) | ((u32)f2bf(hi) << 16);
#endif
}
__device__ __forceinline__ float silu_f(float x) {
    return x * __builtin_amdgcn_rcpf(1.0f + __expf(-x));
}
__device__ __forceinline__ bf16x8 ldfrag(const u16* p) {
    return *(const bf16x8*)__builtin_assume_aligned(p, 16);
}
__device__ __forceinline__ u64 shfl_xor_u64(u64 v, int mask) {
    u32 lo = (u32)v, hi = (u32)(v >> 32);
    lo = (u32)__shfl_xor((int)lo, mask, 64);
    hi = (u32)__shfl_xor((int)hi, mask, 64);
    return ((u64)hi << 32) | lo;
}

// ---------------------------------------------------------------------------
// K0: dtype probe (fp32 vs bf16 float inputs)
// ---------------------------------------------------------------------------
__global__ void probe_kernel(const u16* __restrict__ raw, int* __restrict__ flag) {
    __shared__ int s;
    int t = threadIdx.x;
    if (t == 0) s = 0;
    __syncthreads();
    float x = bf2f(raw[2 * t]);
    if (!(fabsf(x) < 1000.0f)) atomicOr(&s, 1);
    __syncthreads();
    if (t == 0) *flag = s;
}

// ---------------------------------------------------------------------------
// K0b: ingest small fp32-canonical arrays.
// ---------------------------------------------------------------------------
#define NARR 10
struct IngestDesc {
    const void* src[NARR];
    void*       dst[NARR];
    int         n[NARR];
};

__global__ void ingest_kernel(IngestDesc d, const int* __restrict__ flag, int total) {
    int gid = blockIdx.x * blockDim.x + threadIdx.x;
    if (gid >= total) return;
    int a = 0, off = gid;
    while (off >= d.n[a]) { off -= d.n[a]; ++a; }
    bool f32in = (*flag != 0);
    float v = f32in ? ((const float*)d.src[a])[off]
                    : bf2f(((const u16*)d.src[a])[off]);
    ((float*)d.dst[a])[off] = v;
}

// ---------------------------------------------------------------------------
// K0c: weight prep — transpose to [n][k] bf16 for MFMA B-operands.
// ---------------------------------------------------------------------------
__global__ void prep_weights(const void* __restrict__ l1w, const void* __restrict__ l2w,
                             const void* __restrict__ mw2, const void* __restrict__ mw1,
                             u16* __restrict__ l1wt, u16* __restrict__ l2wt,
                             u16* __restrict__ mw2t, u16* __restrict__ mw1t,
                             const int* __restrict__ flag) {
    int gid = blockIdx.x * blockDim.x + threadIdx.x;
    bool f32in = (*flag != 0);
    if (gid < 3 * 98304) {
        int seg = gid / 98304;
        int t = gid % 98304;
        int l = t >> 14;
        int n = (t >> 7) & 127;
        int k = t & 127;
        const void* src = (seg == 0) ? l1w : ((seg == 1) ? l2w : mw2);
        u16* dst = (seg == 0) ? l1wt : ((seg == 1) ? l2wt : mw2t);
        int si = l * 16384 + k * 128 + n;
        float v = f32in ? ((const float*)src)[si] : bf2f(((const u16*)src)[si]);
        dst[t] = f2bf(v);
    } else {
        int t = gid - 3 * 98304;
        if (t < 49152) {
            int l = t >> 13;
            int n = (t >> 6) & 127;
            int k = t & 63;
            float v = 0.0f;
            if (k < 50) {
                int si = l * 6400 + k * 128 + n;
                v = f32in ? ((const float*)mw1)[si] : bf2f(((const u16*)mw1)[si]);
            }
            mw1t[t] = f2bf(v);
        }
    }
}

// ---------------------------------------------------------------------------
// K1: graph build, one WAVE per center atom. u64 (d2,j) keys, butterfly min
// x32 == jax.lax.top_k order. Also builds reverse adjacency.
// ---------------------------------------------------------------------------
__launch_bounds__(256)
__global__ void build_graph_kernel(const float* __restrict__ pos,
                                   float* __restrict__ dist,
                                   float* __restrict__ cvalp,
                                   int* __restrict__ rev_cnt,
                                   int* __restrict__ rev_e) {
    int wv = threadIdx.x >> 6, lane = threadIdx.x & 63;
    int t = blockIdx.x * 4 + wv;
    int tl = t & 127;
    int base = t & ~127;
    float cx = pos[t * 3 + 0];
    float cy = pos[t * 3 + 1];
    float cz = pos[t * 3 + 2];
    u64 key[2];
#pragma unroll
    for (int c = 0; c < 2; ++c) {
        int j = lane + c * 64;
        float jx = pos[(base + j) * 3 + 0];
        float jy = pos[(base + j) * 3 + 1];
        float jz = pos[(base + j) * 3 + 2];
        float dx = __fsub_rn(cx, jx);
        float dy = __fsub_rn(cy, jy);
        float dz = __fsub_rn(cz, jz);
        float d2 = __fadd_rn(__fadd_rn(__fmul_rn(dx, dx), __fmul_rn(dy, dy)),
                             __fmul_rn(dz, dz));
        bool valid = (j != tl) && (d2 < 100.0f);
        key[c] = valid ? ((((u64)__float_as_uint(d2)) << 32) | (u32)j) : ~0ULL;
    }
    for (int k = 0; k < KNN; ++k) {
        u64 m = key[0] < key[1] ? key[0] : key[1];
#pragma unroll
        for (int off = 32; off > 0; off >>= 1) {
            u64 o = shfl_xor_u64(m, off);
            if (o < m) m = o;
        }
        int e = t * KNN + k;
        if (m == ~0ULL) {
            if (lane == 0) { dist[e] = 1.0f; cvalp[e] = 0.0f; }
        } else {
            if (key[0] == m) key[0] = ~0ULL;
            if (key[1] == m) key[1] = ~0ULL;
            if (lane == (int)(m & 63)) {
                float d2 = __uint_as_float((u32)(m >> 32));
                float d = __fsqrt_rn(d2);
                float cv = (d < 10.0f) ? 0.5f * (cosf(d * 3.14159265f / 10.0f) + 1.0f)
                                       : 0.0f;
                dist[e] = d;
                cvalp[e] = cv;
                int j = base + (int)(m & 0xffffffffu);
                int p = atomicAdd(&rev_cnt[j], 1);
                rev_e[(size_t)j * 128 + p] = e;
            }
        }
    }
}

// ---------------------------------------------------------------------------
// K1b: slot builder — pad each receiver's edge list into 32-edge slots.
// slot_counter doubles as n_slots. Sum ceil(deg/32) <= 16384.
// ---------------------------------------------------------------------------
__global__ void build_slots(const int* __restrict__ rev_cnt,
                            const int* __restrict__ rev_e,
                            int* __restrict__ slot_recv,
                            int* __restrict__ slot_edges,
                            int* __restrict__ slot_counter) {
    int j = blockIdx.x * 256 + threadIdx.x;
    if (j >= NATOMS) return;
    int n = rev_cnt[j];
    int ns = (n + 31) >> 5;
    if (ns == 0) return;
    int base = atomicAdd(slot_counter, ns);
    const int* lst = rev_e + (size_t)j * 128;
    for (int s = 0; s < ns; ++s) {
        slot_recv[base + s] = j;
        int* dst = slot_edges + (size_t)(base + s) * 32;
        for (int k = 0; k < 32; ++k) {
            int idx = s * 32 + k;
            dst[k] = (idx < n) ? lst[idx] : -1;
        }
    }
}

// ---------------------------------------------------------------------------
// K2: embedding gather
// ---------------------------------------------------------------------------
__global__ void embed_kernel(const int* __restrict__ z,
                             const float* __restrict__ emb,
                             float* __restrict__ h) {
    int i = blockIdx.x, t = threadIdx.x;
    h[(size_t)i * HID + t] = emb[(size_t)z[i] * HID + t];
}

// ---------------------------------------------------------------------------
// K3: dense MFMA GEMM, O[8192,128] = A @ Bt^T + bias. SPLIT=1: A as hi+lo
// bf16 pair (fp32-ish precision, h path). SPLIT=0: single bf16 (xj path).
// MODE 0: O = res; MODE 1: O += silu(res).
// ---------------------------------------------------------------------------
template <int MODE, int SPLIT>
__launch_bounds__(256)
__global__ void gemm_mfma(const float* __restrict__ A,
                          const u16* __restrict__ Bt,
                          const float* __restrict__ bias,
                          float* __restrict__ O) {
    __shared__ u16 s_ahi[32 * PAD128];
    __shared__ u16 s_alo[SPLIT ? 32 * PAD128 : 2];
    __shared__ u16 s_b[128 * PAD128];
    __shared__ float s_bias[128];
    int tid = threadIdx.x;
    int row0 = blockIdx.x * 32;
    {
        const float4* src = (const float4*)(A + (size_t)row0 * 128);
        for (int p = 0; p < 4; ++p) {
            int q = tid + p * 256;
            int r = q >> 5, k4 = (q & 31) * 4;
            float4 v = src[q];
            u32 h0 = pkbf(v.x, v.y), h1 = pkbf(v.z, v.w);
            u32* hd = (u32*)&s_ahi[r * PAD128 + k4];
            hd[0] = h0; hd[1] = h1;
            if (SPLIT) {
                u32 l0 = pkbf(v.x - bf2f((u16)h0), v.y - bf2f((u16)(h0 >> 16)));
                u32 l1 = pkbf(v.z - bf2f((u16)h1), v.w - bf2f((u16)(h1 >> 16)));
                u32* ld = (u32*)&s_alo[r * PAD128 + k4];
                ld[0] = l0; ld[1] = l1;
            }
        }
    }
    {
        const uint4* src = (const uint4*)Bt;
        for (int p = 0; p < 8; ++p) {
            int q = tid + p * 256;
            int r = q >> 4, c8 = (q & 15) * 8;
            *(uint4*)&s_b[r * PAD128 + c8] = src[q];
        }
    }
    if (tid < 128) s_bias[tid] = bias[tid];
    __syncthreads();

    int wv = tid >> 6, lane = tid & 63;
    int quad = lane >> 4, lr = lane & 15;
    int n0 = wv * 32;
    f32x4 acc[2][2];
#pragma unroll
    for (int mt = 0; mt < 2; ++mt)
#pragma unroll
        for (int nt = 0; nt < 2; ++nt) acc[mt][nt] = (f32x4){0.f, 0.f, 0.f, 0.f};
#pragma unroll
    for (int kk = 0; kk < 128; kk += 32) {
        bf16x8 ah0 = ldfrag(&s_ahi[(lr)      * PAD128 + kk + quad * 8]);
        bf16x8 ah1 = ldfrag(&s_ahi[(16 + lr) * PAD128 + kk + quad * 8]);
#pragma unroll
        for (int nt = 0; nt < 2; ++nt) {
            bf16x8 b = ldfrag(&s_b[(n0 + nt * 16 + lr) * PAD128 + kk + quad * 8]);
            acc[0][nt] = __builtin_amdgcn_mfma_f32_16x16x32_bf16(ah0, b, acc[0][nt], 0, 0, 0);
            acc[1][nt] = __builtin_amdgcn_mfma_f32_16x16x32_bf16(ah1, b, acc[1][nt], 0, 0, 0);
        }
        if (SPLIT) {
            bf16x8 al0 = ldfrag(&s_alo[(lr)      * PAD128 + kk + quad * 8]);
            bf16x8 al1 = ldfrag(&s_alo[(16 + lr) * PAD128 + kk + quad * 8]);
#pragma unroll
            for (int nt = 0; nt < 2; ++nt) {
                bf16x8 b = ldfrag(&s_b[(n0 + nt * 16 + lr) * PAD128 + kk + quad * 8]);
                acc[0][nt] = __builtin_amdgcn_mfma_f32_16x16x32_bf16(al0, b, acc[0][nt], 0, 0, 0);
                acc[1][nt] = __builtin_amdgcn_mfma_f32_16x16x32_bf16(al1, b, acc[1][nt], 0, 0, 0);
            }
        }
    }
#pragma unroll
    for (int mt = 0; mt < 2; ++mt)
#pragma unroll
        for (int nt = 0; nt < 2; ++nt)
#pragma unroll
            for (int r = 0; r < 4; ++r) {
                int grow = row0 + mt * 16 + quad * 4 + r;
                int col = n0 + nt * 16 + lr;
                float v = acc[mt][nt][r] + s_bias[col];
                size_t off = (size_t)grow * 128 + col;
                if (MODE == 0) O[off] = v;
                else           O[off] += silu_f(v);
            }
}

// ---------------------------------------------------------------------------
// K4: fused W-compute + aggregation. One wave per SLOT (32 same-receiver
// edges). Barrier-free: per-wave staging, per-wave t1 LDS region, per-wave
// M staging (reuses t1), coalesced xj row loads (src wave-uniform per row),
// fp32 column sums, 2 atomics/lane into agg. No msg materialization.
// ---------------------------------------------------------------------------
__launch_bounds__(256)
__global__ void wagg_kernel(const float* __restrict__ dist,
                            const float* __restrict__ cval,
                            const float* __restrict__ xj,     // [8192][128] f32
                            const u16* __restrict__ mw1t,     // [128][64]
                            const u16* __restrict__ mw2t,     // [128][128]
                            const float* __restrict__ b1,
                            const float* __restrict__ b2,
                            const int* __restrict__ slot_recv,
                            const int* __restrict__ slot_edges,
                            const int* __restrict__ n_slots,
                            float* __restrict__ agg) {
    __shared__ u16 s_t1[128 * PAD128];     // 34.8 KB: t1 then M, per-wave rows
    __shared__ int   s_ed[128];
    __shared__ float s_d[128];
    __shared__ float s_cv[128];

    int tid = threadIdx.x;
    int wv = tid >> 6, lane = tid & 63;
    int slot = blockIdx.x * 4 + wv;
    int ns = *n_slots;
    if (slot >= ns) return;               // wave-uniform, no barriers anywhere

    // per-wave staging (same-wave DS ordering; compiler inserts lgkmcnt)
    if (lane < 32) {
        int e = slot_edges[(size_t)slot * 32 + lane];
        s_ed[wv * 32 + lane] = e;
        s_d[wv * 32 + lane]  = (e >= 0) ? dist[e] : 1.0e4f;
        s_cv[wv * 32 + lane] = (e >= 0) ? cval[e] : 0.0f;
    }

    int quad = lane >> 4, lr = lane & 15;
    int m0 = wv * 32;

    // Phase A: t1 = silu(rbf @ mw1 + b1), rbf per-lane in registers
    {
        const float wgi = 49.0f / 10.0f;
        union U8 { bf16x8 v; u32 w[4]; };
        U8 afr[2][2];
#pragma unroll
        for (int mt = 0; mt < 2; ++mt) {
            float u = s_d[m0 + mt * 16 + lr] * wgi;
            float kb = (float)(quad * 8);
#pragma unroll
            for (int kki = 0; kki < 2; ++kki) {
                float t0 = u - kb - (float)(kki * 32);
                float vj[8];
#pragma unroll
                for (int j = 0; j < 8; ++j) {
                    float tt = t0 - (float)j;
                    float e = __expf(-0.5f * tt * tt);
                    if (kki == 1 && (quad * 8 + j) >= 18) e = 0.0f;  // k>=50 pad
                    vj[j] = e;
                }
#pragma unroll
                for (int p = 0; p < 4; ++p)
                    afr[mt][kki].w[p] = pkbf(vj[2 * p], vj[2 * p + 1]);
            }
        }
        f32x4 accA[2][8];
#pragma unroll
        for (int mt = 0; mt < 2; ++mt)
#pragma unroll
            for (int nt = 0; nt < 8; ++nt) accA[mt][nt] = (f32x4){0.f, 0.f, 0.f, 0.f};
#pragma unroll
        for (int kki = 0; kki < 2; ++kki) {
#pragma unroll
            for (int nt = 0; nt < 8; ++nt) {
                bf16x8 b = ldfrag(mw1t + (nt * 16 + lr) * 64 + kki * 32 + quad * 8);
                accA[0][nt] = __builtin_amdgcn_mfma_f32_16x16x32_bf16(afr[0][kki].v, b, accA[0][nt], 0, 0, 0);
                accA[1][nt] = __builtin_amdgcn_mfma_f32_16x16x32_bf16(afr[1][kki].v, b, accA[1][nt], 0, 0, 0);
            }
        }
#pragma unroll
        for (int mt = 0; mt < 2; ++mt) {
            int r0 = m0 + mt * 16 + quad * 4;
            u16* tp0 = &s_t1[r0 * PAD128 + lr];
#pragma unroll
            for (int nt = 0; nt < 8; ++nt) {
                int col = nt * 16;
                float bb = b1[col + lr];
                u32 p01 = pkbf(silu_f(accA[mt][nt][0] + bb),
                               silu_f(accA[mt][nt][1] + bb));
                u32 p23 = pkbf(silu_f(accA[mt][nt][2] + bb),
                               silu_f(accA[mt][nt][3] + bb));
                u16* tp = tp0 + col;
                tp[0]          = (u16)p01;
                tp[PAD128]     = (u16)(p01 >> 16);
                tp[2 * PAD128] = (u16)p23;
                tp[3 * PAD128] = (u16)(p23 >> 16);
            }
        }
    }

    // Phase B: M = (t1 @ mw2 + b2) * cv, staged bf16 back into wave's region
    {
        f32x4 accB[2][8];
#pragma unroll
        for (int mt = 0; mt < 2; ++mt)
#pragma unroll
            for (int nt = 0; nt < 8; ++nt) accB[mt][nt] = (f32x4){0.f, 0.f, 0.f, 0.f};
#pragma unroll
        for (int kk = 0; kk < 128; kk += 32) {
            bf16x8 a0 = ldfrag(&s_t1[(m0 + lr)      * PAD128 + kk + quad * 8]);
            bf16x8 a1 = ldfrag(&s_t1[(m0 + 16 + lr) * PAD128 + kk + quad * 8]);
#pragma unroll
            for (int nt = 0; nt < 8; ++nt) {
                bf16x8 b = ldfrag(mw2t + (nt * 16 + lr) * 128 + kk + quad * 8);
                accB[0][nt] = __builtin_amdgcn_mfma_f32_16x16x32_bf16(a0, b, accB[0][nt], 0, 0, 0);
                accB[1][nt] = __builtin_amdgcn_mfma_f32_16x16x32_bf16(a1, b, accB[1][nt], 0, 0, 0);
            }
        }
        // overwrite this wave's t1 rows with M (all t1 reads above are older
        // same-wave DS ops -> in-order LDS pipeline makes this safe)
#pragma unroll
        for (int mt = 0; mt < 2; ++mt) {
            int r0 = m0 + mt * 16 + quad * 4;
            float c0 = s_cv[r0], c1 = s_cv[r0 + 1], c2 = s_cv[r0 + 2], c3 = s_cv[r0 + 3];
            u16* bp = &s_t1[r0 * PAD128 + lr];
#pragma unroll
            for (int nt = 0; nt < 8; ++nt) {
                int col = nt * 16;
                float bb = b2[col + lr];
                u32 p01 = pkbf((accB[mt][nt][0] + bb) * c0,
                               (accB[mt][nt][1] + bb) * c1);
                u32 p23 = pkbf((accB[mt][nt][2] + bb) * c2,
                               (accB[mt][nt][3] + bb) * c3);
                bp[col]              = (u16)p01;
                bp[col + PAD128]     = (u16)(p01 >> 16);
                bp[col + 2 * PAD128] = (u16)p23;
                bp[col + 3 * PAD128] = (u16)(p23 >> 16);
            }
        }
    }

    // Pass 2: agg[j] += sum_rows M[row] * xj[src(row)]. src wave-uniform per
    // row -> coalesced float2 xj loads; fp32 accumulate; 2 atomics/lane.
    {
        int j = slot_recv[slot];
        const u16* sm = &s_t1[m0 * PAD128];
        float a0 = 0.f, a1 = 0.f;
#pragma unroll 4
        for (int row = 0; row < 32; ++row) {
            int e = s_ed[m0 + row];
            if (e < 0) continue;                   // wave-uniform pad skip
            int src = e >> 5;                      // edge e = center*32 + k
            ushort2 m = *(const ushort2*)&sm[row * PAD128 + lane * 2];
            float2 xv = *(const float2*)(xj + (size_t)src * 128 + lane * 2);
            a0 += bf2f(m.x) * xv.x;
            a1 += bf2f(m.y) * xv.y;
        }
        float* dst = agg + (size_t)j * 128 + lane * 2;
        atomicAdd(dst,     a0);
        atomicAdd(dst + 1, a1);
    }
}

// ---------------------------------------------------------------------------
// K6: output head — 16 atoms/block, LDS-tiled, one atomic per block.
// ---------------------------------------------------------------------------
__launch_bounds__(256)
__global__ void head_kernel(const float* __restrict__ h,
                            const float* __restrict__ ow1,
                            const float* __restrict__ ob1,
                            const float* __restrict__ ow2,
                            const float* __restrict__ ob2,
                            float* __restrict__ gsum) {
    __shared__ __align__(16) float s_w[128 * 64];   // [f][c], 32 KB
    __shared__ __align__(16) float s_h[16 * 132];
    __shared__ float s_sum;
    int tid = threadIdx.x;
    int a0 = blockIdx.x * 16;
    if (tid == 0) s_sum = 0.0f;
    {
        const float4* src = (const float4*)ow1;
        float4* dst = (float4*)s_w;
#pragma unroll
        for (int p = 0; p < 8; ++p) dst[tid + p * 256] = src[tid + p * 256];
    }
    {
        const float4* src = (const float4*)(h + (size_t)a0 * 128);
#pragma unroll
        for (int p = 0; p < 2; ++p) {
            int q = tid + p * 256;
            int r = q >> 5, c4 = (q & 31) * 4;
            *(float4*)&s_h[r * 132 + c4] = src[q];
        }
    }
    __syncthreads();
    int atom = tid >> 4, cg = tid & 15;
    const float* hr = &s_h[atom * 132];
    const float4* w4 = (const float4*)s_w;
    float4 acc = {0.f, 0.f, 0.f, 0.f};
#pragma unroll 8
    for (int f = 0; f < 128; ++f) {
        float hv = hr[f];
        float4 w = w4[f * 16 + cg];
        acc.x += hv * w.x; acc.y += hv * w.y;
        acc.z += hv * w.z; acc.w += hv * w.w;
    }
    int c0 = cg * 4;
    float v = silu_f(acc.x + ob1[c0 + 0]) * ow2[c0 + 0]
            + silu_f(acc.y + ob1[c0 + 1]) * ow2[c0 + 1]
            + silu_f(acc.z + ob1[c0 + 2]) * ow2[c0 + 2]
            + silu_f(acc.w + ob1[c0 + 3]) * ow2[c0 + 3];
    v += __shfl_xor(v, 1, 64);
    v += __shfl_xor(v, 2, 64);
    v += __shfl_xor(v, 4, 64);
    v += __shfl_xor(v, 8, 64);
    if ((tid & 15) == 0) atomicAdd(&s_sum, v + ob2[0]);
    __syncthreads();
    if (tid == 0) atomicAdd(&gsum[a0 >> 7], s_sum);
}

__global__ void finalize_kernel(const float* __restrict__ gsum, void* __restrict__ out,
                                const int* __restrict__ flag) {
    int t = threadIdx.x;
    if (*flag) ((float*)out)[t] = gsum[t];
    else       ((u16*)out)[t]   = f2bf(gsum[t]);
}

// ---------------------------------------------------------------------------
extern "C" void kernel_launch(void* const* d_in, const int* in_sizes, int n_in,
                              void* d_out, int out_size, void* d_ws, size_t ws_size,
                              hipStream_t stream) {
    const void* pos  = d_in[0];
    const int*  z    = (const int*)d_in[1];
    // d_in[2] = batch (implicit: graph = i >> 7)
    const void* emb  = d_in[3];
    const void* mw1  = d_in[4];
    const void* mb1  = d_in[5];
    const void* mw2  = d_in[6];
    const void* mb2  = d_in[7];
    const void* l1w  = d_in[8];
    const void* l1b  = d_in[9];
    const void* l2w  = d_in[10];
    const void* l2b  = d_in[11];
    const void* ow1  = d_in[12];
    const void* ob1  = d_in[13];
    const void* ow2  = d_in[14];
    const void* ob2  = d_in[15];

    char* ws = (char*)d_ws;
    const size_t KB = 1024, MB = 1048576;
    int*   w_flag  = (int*)  (ws);
    float* c_pos   = (float*)(ws + 4   * KB);
    float* c_emb   = (float*)(ws + 112 * KB);
    float* c_mb1   = (float*)(ws + 168 * KB);
    float* c_mb2   = (float*)(ws + 172 * KB);
    float* c_l1b   = (float*)(ws + 176 * KB);
    float* c_l2b   = (float*)(ws + 180 * KB);
    float* c_ow1   = (float*)(ws + 184 * KB);
    float* c_ob1   = (float*)(ws + 220 * KB);
    float* c_ow2   = (float*)(ws + 221 * KB);
    float* c_ob2   = (float*)(ws + 222 * KB);
    float* w_gsum  = (float*)(ws + 224 * KB);
    u16*   c_l1wt  = (u16*)  (ws + 256 * KB);
    u16*   c_l2wt  = (u16*)  (ws + 448 * KB);
    u16*   c_mw2t  = (u16*)  (ws + 640 * KB);
    u16*   c_mw1t  = (u16*)  (ws + 832 * KB);
    float* w_dist  = (float*)(ws + 1  * MB);
    float* w_cval  = (float*)(ws + 2  * MB);
    int*   rev_cnt = (int*)  (ws + 3  * MB);            // 32 KB
    int*   w_slotc = (int*)  (ws + 3  * MB + 32 * KB);  // slot counter (4 B)
    int*   rev_e   = (int*)  (ws + 4  * MB);            // 4 MB
    float* w_h     = (float*)(ws + 8  * MB);
    float* w_xj    = (float*)(ws + 12 * MB);
    float* w_agg   = (float*)(ws + 16 * MB);
    int*   slot_recv  = (int*)(ws + 20 * MB);           // 64 KB
    int*   slot_edges = (int*)(ws + 21 * MB);           // 2 MB

    hipMemsetAsync(rev_cnt, 0, NATOMS * sizeof(int) + 4, stream);  // + counter
    hipMemsetAsync(w_gsum, 0, GRAPHS * sizeof(float), stream);

    probe_kernel<<<1, 256, 0, stream>>>((const u16*)emb, w_flag);

    IngestDesc dsc;
    const void* srcs[NARR] = {pos, emb, mb1, mb2, l1b, l2b, ow1, ob1, ow2, ob2};
    void* dsts[NARR] = {c_pos, c_emb, c_mb1, c_mb2, c_l1b, c_l2b, c_ow1, c_ob1,
                        c_ow2, c_ob2};
    int ns_[NARR] = {24576, 12800, 768, 768, 768, 768, 8192, 64, 64, 1};
    int total = 0;
    for (int a = 0; a < NARR; ++a) {
        dsc.src[a] = srcs[a]; dsc.dst[a] = dsts[a]; dsc.n[a] = ns_[a];
        total += ns_[a];
    }
    ingest_kernel<<<(total + 255) / 256, 256, 0, stream>>>(dsc, w_flag, total);
    prep_weights<<<1344, 256, 0, stream>>>(l1w, l2w, mw2, mw1,
                                           c_l1wt, c_l2wt, c_mw2t, c_mw1t, w_flag);

    build_graph_kernel<<<NATOMS / 4, 256, 0, stream>>>(c_pos, w_dist, w_cval,
                                                       rev_cnt, rev_e);
    build_slots<<<NATOMS / 256, 256, 0, stream>>>(rev_cnt, rev_e,
                                                  slot_recv, slot_edges, w_slotc);
    embed_kernel<<<NATOMS, HID, 0, stream>>>(z, c_emb, w_h);

    for (int l = 0; l < LAYERS; ++l) {
        gemm_mfma<0, 0><<<NATOMS / 32, 256, 0, stream>>>(
            w_h, c_l1wt + (size_t)l * 16384, c_l1b + (size_t)l * 128, w_xj);
        hipMemsetAsync(w_agg, 0, (size_t)NATOMS * HID * sizeof(float), stream);
        wagg_kernel<<<MAXSLOTS / 4, 256, 0, stream>>>(
            w_dist, w_cval, w_xj,
            c_mw1t + (size_t)l * 8192, c_mw2t + (size_t)l * 16384,
            c_mb1 + (size_t)l * 128, c_mb2 + (size_t)l * 128,
            slot_recv, slot_edges, w_slotc, w_agg);
        gemm_mfma<1, 1><<<NATOMS / 32, 256, 0, stream>>>(
            w_agg, c_l2wt + (size_t)l * 16384, c_l2b + (size_t)l * 128, w_h);
    }

    head_kernel<<<NATOMS / 16, 256, 0, stream>>>(w_h, c_ow1, c_ob1, c_ow2, c_ob2,
                                                 w_gsum);
    finalize_kernel<<<1, GRAPHS, 0, stream>>>(w_gsum, (void*)d_out, w_flag);
}

// Round 8
// 694.552 us; speedup vs baseline: 1.4101x; 1.4101x over previous
//
#include <hip/hip_runtime.h>
#include <math.h>

typedef unsigned short u16;
typedef unsigned int   u32;
typedef unsigned long long u64;

#define NATOMS 8192
#define GRAPHS 64
#define APG    128
#define KNN    32
#define NGAUSS 50
#define HID    128
#define LAYERS 6
#define PAD128 136

typedef __attribute__((ext_vector_type(8))) short bf16x8;
typedef __attribute__((ext_vector_type(4))) float f32x4;

__device__ __forceinline__ float bf2f(u16 v) {
    return __uint_as_float(((u32)v) << 16);
}
__device__ __forceinline__ u16 f2bf(float f) {
    u32 u = __float_as_uint(f);
    u32 lsb = (u >> 16) & 1u;
    u += 0x7fffu + lsb;
    return (u16)(u >> 16);
}
__device__ __forceinline__ u32 pkbf(float lo, float hi) {
#if __has_builtin(__builtin_amdgcn_cvt_pk_bf16_f32)
    auto r = __builtin_amdgcn_cvt_pk_bf16_f32(lo, hi);
    u32 u; __builtin_memcpy(&u, &r, 4); return u;
#else
    return (u32)f2bf(lo) | ((u32)f2bf(hi) << 16);
#endif
}
__device__ __forceinline__ float silu_f(float x) {
    return x * __builtin_amdgcn_rcpf(1.0f + __expf(-x));
}
__device__ __forceinline__ bf16x8 ldfrag(const u16* p) {
    return *(const bf16x8*)__builtin_assume_aligned(p, 16);
}
__device__ __forceinline__ u64 shfl_xor_u64(u64 v, int mask) {
    u32 lo = (u32)v, hi = (u32)(v >> 32);
    lo = (u32)__shfl_xor((int)lo, mask, 64);
    hi = (u32)__shfl_xor((int)hi, mask, 64);
    return ((u64)hi << 32) | lo;
}

// ---------------------------------------------------------------------------
// K0: dtype probe (fp32 vs bf16 float inputs)
// ---------------------------------------------------------------------------
__global__ void probe_kernel(const u16* __restrict__ raw, int* __restrict__ flag) {
    __shared__ int s;
    int t = threadIdx.x;
    if (t == 0) s = 0;
    __syncthreads();
    float x = bf2f(raw[2 * t]);
    if (!(fabsf(x) < 1000.0f)) atomicOr(&s, 1);
    __syncthreads();
    if (t == 0) *flag = s;
}

// ---------------------------------------------------------------------------
// K0b: ingest small fp32-canonical arrays.
// ---------------------------------------------------------------------------
#define NARR 10
struct IngestDesc {
    const void* src[NARR];
    void*       dst[NARR];
    int         n[NARR];
};

__global__ void ingest_kernel(IngestDesc d, const int* __restrict__ flag, int total) {
    int gid = blockIdx.x * blockDim.x + threadIdx.x;
    if (gid >= total) return;
    int a = 0, off = gid;
    while (off >= d.n[a]) { off -= d.n[a]; ++a; }
    bool f32in = (*flag != 0);
    float v = f32in ? ((const float*)d.src[a])[off]
                    : bf2f(((const u16*)d.src[a])[off]);
    ((float*)d.dst[a])[off] = v;
}

// ---------------------------------------------------------------------------
// K0c: weight prep — transpose to [n][k] bf16 for MFMA B-operands.
// ---------------------------------------------------------------------------
__global__ void prep_weights(const void* __restrict__ l1w, const void* __restrict__ l2w,
                             const void* __restrict__ mw2, const void* __restrict__ mw1,
                             u16* __restrict__ l1wt, u16* __restrict__ l2wt,
                             u16* __restrict__ mw2t, u16* __restrict__ mw1t,
                             const int* __restrict__ flag) {
    int gid = blockIdx.x * blockDim.x + threadIdx.x;
    bool f32in = (*flag != 0);
    if (gid < 3 * 98304) {
        int seg = gid / 98304;
        int t = gid % 98304;
        int l = t >> 14;
        int n = (t >> 7) & 127;
        int k = t & 127;
        const void* src = (seg == 0) ? l1w : ((seg == 1) ? l2w : mw2);
        u16* dst = (seg == 0) ? l1wt : ((seg == 1) ? l2wt : mw2t);
        int si = l * 16384 + k * 128 + n;
        float v = f32in ? ((const float*)src)[si] : bf2f(((const u16*)src)[si]);
        dst[t] = f2bf(v);
    } else {
        int t = gid - 3 * 98304;
        if (t < 49152) {
            int l = t >> 13;
            int n = (t >> 6) & 127;
            int k = t & 63;
            float v = 0.0f;
            if (k < 50) {
                int si = l * 6400 + k * 128 + n;
                v = f32in ? ((const float*)mw1)[si] : bf2f(((const u16*)mw1)[si]);
            }
            mw1t[t] = f2bf(v);
        }
    }
}

// ---------------------------------------------------------------------------
// K1: graph build, one WAVE per center atom. u64 (d2,j) keys, butterfly min
// x32 == jax.lax.top_k order. Also builds reverse adjacency (cv>0 edges).
// ---------------------------------------------------------------------------
__launch_bounds__(256)
__global__ void build_graph_kernel(const float* __restrict__ pos,
                                   float* __restrict__ dist,
                                   float* __restrict__ cvalp,
                                   int* __restrict__ rev_cnt,
                                   int* __restrict__ rev_e) {
    int wv = threadIdx.x >> 6, lane = threadIdx.x & 63;
    int t = blockIdx.x * 4 + wv;
    int tl = t & 127;
    int base = t & ~127;
    float cx = pos[t * 3 + 0];
    float cy = pos[t * 3 + 1];
    float cz = pos[t * 3 + 2];
    u64 key[2];
#pragma unroll
    for (int c = 0; c < 2; ++c) {
        int j = lane + c * 64;
        float jx = pos[(base + j) * 3 + 0];
        float jy = pos[(base + j) * 3 + 1];
        float jz = pos[(base + j) * 3 + 2];
        float dx = __fsub_rn(cx, jx);
        float dy = __fsub_rn(cy, jy);
        float dz = __fsub_rn(cz, jz);
        float d2 = __fadd_rn(__fadd_rn(__fmul_rn(dx, dx), __fmul_rn(dy, dy)),
                             __fmul_rn(dz, dz));
        bool valid = (j != tl) && (d2 < 100.0f);
        key[c] = valid ? ((((u64)__float_as_uint(d2)) << 32) | (u32)j) : ~0ULL;
    }
    for (int k = 0; k < KNN; ++k) {
        u64 m = key[0] < key[1] ? key[0] : key[1];
#pragma unroll
        for (int off = 32; off > 0; off >>= 1) {
            u64 o = shfl_xor_u64(m, off);
            if (o < m) m = o;
        }
        int e = t * KNN + k;
        if (m == ~0ULL) {
            if (lane == 0) { dist[e] = 1.0f; cvalp[e] = 0.0f; }
        } else {
            if (key[0] == m) key[0] = ~0ULL;
            if (key[1] == m) key[1] = ~0ULL;
            if (lane == (int)(m & 63)) {
                float d2 = __uint_as_float((u32)(m >> 32));
                float d = __fsqrt_rn(d2);
                float cv = (d < 10.0f) ? 0.5f * (cosf(d * 3.14159265f / 10.0f) + 1.0f)
                                       : 0.0f;
                dist[e] = d;
                cvalp[e] = cv;
                int j = base + (int)(m & 0xffffffffu);
                int p = atomicAdd(&rev_cnt[j], 1);
                rev_e[(size_t)j * 128 + p] = e;
            }
        }
    }
}

// ---------------------------------------------------------------------------
// K1b: exclusive prefix scan of rev_cnt -> roff (single block, 8192 entries).
// ---------------------------------------------------------------------------
__launch_bounds__(256)
__global__ void scan_offsets(const int* __restrict__ rev_cnt,
                             int* __restrict__ roff,
                             int* __restrict__ ne_out) {
    __shared__ int part[256];
    int t = threadIdx.x;
    int base = t * 32;
    int loc[32];
    int s = 0;
#pragma unroll
    for (int i = 0; i < 32; ++i) { loc[i] = s; s += rev_cnt[base + i]; }
    part[t] = s;
    __syncthreads();
    for (int off = 1; off < 256; off <<= 1) {
        int v = (t >= off) ? part[t - off] : 0;
        __syncthreads();
        part[t] += v;
        __syncthreads();
    }
    int pre = (t == 0) ? 0 : part[t - 1];
#pragma unroll
    for (int i = 0; i < 32; ++i) roff[base + i] = pre + loc[i];
    if (t == 255) *ne_out = part[255];
}

// ---------------------------------------------------------------------------
// K1c: flatten rev lists into receiver-sorted edge array (+ receiver map).
// ---------------------------------------------------------------------------
__global__ void fill_eord(const int* __restrict__ rev_cnt,
                          const int* __restrict__ rev_e,
                          const int* __restrict__ roff,
                          int* __restrict__ eord,
                          int* __restrict__ erecv) {
    int j = blockIdx.x * 256 + threadIdx.x;
    if (j >= NATOMS) return;
    int n = rev_cnt[j], base = roff[j];
    const int* lst = rev_e + (size_t)j * 128;
    for (int k = 0; k < n; ++k) {
        eord[base + k]  = lst[k];
        erecv[base + k] = j;
    }
}

// ---------------------------------------------------------------------------
// K2: embedding gather
// ---------------------------------------------------------------------------
__global__ void embed_kernel(const int* __restrict__ z,
                             const float* __restrict__ emb,
                             float* __restrict__ h) {
    int i = blockIdx.x, t = threadIdx.x;
    h[(size_t)i * HID + t] = emb[(size_t)z[i] * HID + t];
}

// ---------------------------------------------------------------------------
// K3: dense MFMA GEMM (unchanged from R6).
// ---------------------------------------------------------------------------
template <int MODE, int SPLIT>
__launch_bounds__(256)
__global__ void gemm_mfma(const float* __restrict__ A,
                          const u16* __restrict__ Bt,
                          const float* __restrict__ bias,
                          float* __restrict__ O) {
    __shared__ u16 s_ahi[32 * PAD128];
    __shared__ u16 s_alo[SPLIT ? 32 * PAD128 : 2];
    __shared__ u16 s_b[128 * PAD128];
    __shared__ float s_bias[128];
    int tid = threadIdx.x;
    int row0 = blockIdx.x * 32;
    {
        const float4* src = (const float4*)(A + (size_t)row0 * 128);
        for (int p = 0; p < 4; ++p) {
            int q = tid + p * 256;
            int r = q >> 5, k4 = (q & 31) * 4;
            float4 v = src[q];
            u32 h0 = pkbf(v.x, v.y), h1 = pkbf(v.z, v.w);
            u32* hd = (u32*)&s_ahi[r * PAD128 + k4];
            hd[0] = h0; hd[1] = h1;
            if (SPLIT) {
                u32 l0 = pkbf(v.x - bf2f((u16)h0), v.y - bf2f((u16)(h0 >> 16)));
                u32 l1 = pkbf(v.z - bf2f((u16)h1), v.w - bf2f((u16)(h1 >> 16)));
                u32* ld = (u32*)&s_alo[r * PAD128 + k4];
                ld[0] = l0; ld[1] = l1;
            }
        }
    }
    {
        const uint4* src = (const uint4*)Bt;
        for (int p = 0; p < 8; ++p) {
            int q = tid + p * 256;
            int r = q >> 4, c8 = (q & 15) * 8;
            *(uint4*)&s_b[r * PAD128 + c8] = src[q];
        }
    }
    if (tid < 128) s_bias[tid] = bias[tid];
    __syncthreads();

    int wv = tid >> 6, lane = tid & 63;
    int quad = lane >> 4, lr = lane & 15;
    int n0 = wv * 32;
    f32x4 acc[2][2];
#pragma unroll
    for (int mt = 0; mt < 2; ++mt)
#pragma unroll
        for (int nt = 0; nt < 2; ++nt) acc[mt][nt] = (f32x4){0.f, 0.f, 0.f, 0.f};
#pragma unroll
    for (int kk = 0; kk < 128; kk += 32) {
        bf16x8 ah0 = ldfrag(&s_ahi[(lr)      * PAD128 + kk + quad * 8]);
        bf16x8 ah1 = ldfrag(&s_ahi[(16 + lr) * PAD128 + kk + quad * 8]);
#pragma unroll
        for (int nt = 0; nt < 2; ++nt) {
            bf16x8 b = ldfrag(&s_b[(n0 + nt * 16 + lr) * PAD128 + kk + quad * 8]);
            acc[0][nt] = __builtin_amdgcn_mfma_f32_16x16x32_bf16(ah0, b, acc[0][nt], 0, 0, 0);
            acc[1][nt] = __builtin_amdgcn_mfma_f32_16x16x32_bf16(ah1, b, acc[1][nt], 0, 0, 0);
        }
        if (SPLIT) {
            bf16x8 al0 = ldfrag(&s_alo[(lr)      * PAD128 + kk + quad * 8]);
            bf16x8 al1 = ldfrag(&s_alo[(16 + lr) * PAD128 + kk + quad * 8]);
#pragma unroll
            for (int nt = 0; nt < 2; ++nt) {
                bf16x8 b = ldfrag(&s_b[(n0 + nt * 16 + lr) * PAD128 + kk + quad * 8]);
                acc[0][nt] = __builtin_amdgcn_mfma_f32_16x16x32_bf16(al0, b, acc[0][nt], 0, 0, 0);
                acc[1][nt] = __builtin_amdgcn_mfma_f32_16x16x32_bf16(al1, b, acc[1][nt], 0, 0, 0);
            }
        }
    }
#pragma unroll
    for (int mt = 0; mt < 2; ++mt)
#pragma unroll
        for (int nt = 0; nt < 2; ++nt)
#pragma unroll
            for (int r = 0; r < 4; ++r) {
                int grow = row0 + mt * 16 + quad * 4 + r;
                int col = n0 + nt * 16 + lr;
                float v = acc[mt][nt][r] + s_bias[col];
                size_t off = (size_t)grow * 128 + col;
                if (MODE == 0) O[off] = v;
                else           O[off] += silu_f(v);
            }
}

// ---------------------------------------------------------------------------
// K4: fused W-compute + aggregation over receiver-SORTED edge tiles.
// One wave per 32-edge tile of eord (no padding). Phases A/B as verified.
// Pass 2: rows receiver-sorted; accumulate fp32 per lane; flush (2 atomics/
// lane) on receiver change — ~2 flushes/wave. Pad rows have cv=0 -> M=0.
// ---------------------------------------------------------------------------
__launch_bounds__(256)
__global__ void wagg_kernel(const float* __restrict__ dist,
                            const float* __restrict__ cval,
                            const float* __restrict__ xj,     // [8192][128] f32
                            const u16* __restrict__ mw1t,     // [128][64]
                            const u16* __restrict__ mw2t,     // [128][128]
                            const float* __restrict__ b1,
                            const float* __restrict__ b2,
                            const int* __restrict__ eord,
                            const int* __restrict__ erecv,
                            const int* __restrict__ ne_ptr,
                            float* __restrict__ agg) {
    __shared__ u16 s_t1[128 * PAD128];     // per-wave 32-row regions
    __shared__ int   s_ed[128];
    __shared__ int   s_rc[128];
    __shared__ float s_d[128];
    __shared__ float s_cv[128];

    int tid = threadIdx.x;
    int wv = tid >> 6, lane = tid & 63;
    int tile = blockIdx.x * 4 + wv;
    int NE = *ne_ptr;
    int ntiles = (NE + 31) >> 5;
    if (tile >= ntiles) return;            // wave-uniform

    if (lane < 32) {
        int gi = tile * 32 + lane;
        bool ok = gi < NE;
        int e = ok ? eord[gi] : -1;
        s_ed[wv * 32 + lane] = e;
        s_rc[wv * 32 + lane] = ok ? erecv[gi] : -1;
        s_d [wv * 32 + lane] = ok ? dist[e] : 1.0e4f;
        s_cv[wv * 32 + lane] = ok ? cval[e] : 0.0f;   // pad -> M = 0
    }

    int quad = lane >> 4, lr = lane & 15;
    int m0 = wv * 32;

    // Phase A: t1 = silu(rbf @ mw1 + b1)
    {
        const float wgi = 49.0f / 10.0f;
        union U8 { bf16x8 v; u32 w[4]; };
        U8 afr[2][2];
#pragma unroll
        for (int mt = 0; mt < 2; ++mt) {
            float u = s_d[m0 + mt * 16 + lr] * wgi;
            float kb = (float)(quad * 8);
#pragma unroll
            for (int kki = 0; kki < 2; ++kki) {
                float t0 = u - kb - (float)(kki * 32);
                float vj[8];
#pragma unroll
                for (int j = 0; j < 8; ++j) {
                    float tt = t0 - (float)j;
                    float e = __expf(-0.5f * tt * tt);
                    if (kki == 1 && (quad * 8 + j) >= 18) e = 0.0f;
                    vj[j] = e;
                }
#pragma unroll
                for (int p = 0; p < 4; ++p)
                    afr[mt][kki].w[p] = pkbf(vj[2 * p], vj[2 * p + 1]);
            }
        }
        f32x4 accA[2][8];
#pragma unroll
        for (int mt = 0; mt < 2; ++mt)
#pragma unroll
            for (int nt = 0; nt < 8; ++nt) accA[mt][nt] = (f32x4){0.f, 0.f, 0.f, 0.f};
#pragma unroll
        for (int kki = 0; kki < 2; ++kki) {
#pragma unroll
            for (int nt = 0; nt < 8; ++nt) {
                bf16x8 b = ldfrag(mw1t + (nt * 16 + lr) * 64 + kki * 32 + quad * 8);
                accA[0][nt] = __builtin_amdgcn_mfma_f32_16x16x32_bf16(afr[0][kki].v, b, accA[0][nt], 0, 0, 0);
                accA[1][nt] = __builtin_amdgcn_mfma_f32_16x16x32_bf16(afr[1][kki].v, b, accA[1][nt], 0, 0, 0);
            }
        }
#pragma unroll
        for (int mt = 0; mt < 2; ++mt) {
            int r0 = m0 + mt * 16 + quad * 4;
            u16* tp0 = &s_t1[r0 * PAD128 + lr];
#pragma unroll
            for (int nt = 0; nt < 8; ++nt) {
                int col = nt * 16;
                float bb = b1[col + lr];
                u32 p01 = pkbf(silu_f(accA[mt][nt][0] + bb),
                               silu_f(accA[mt][nt][1] + bb));
                u32 p23 = pkbf(silu_f(accA[mt][nt][2] + bb),
                               silu_f(accA[mt][nt][3] + bb));
                u16* tp = tp0 + col;
                tp[0]          = (u16)p01;
                tp[PAD128]     = (u16)(p01 >> 16);
                tp[2 * PAD128] = (u16)p23;
                tp[3 * PAD128] = (u16)(p23 >> 16);
            }
        }
    }

    // Phase B: M = (t1 @ mw2 + b2) * cv, staged bf16 in wave's region
    {
        f32x4 accB[2][8];
#pragma unroll
        for (int mt = 0; mt < 2; ++mt)
#pragma unroll
            for (int nt = 0; nt < 8; ++nt) accB[mt][nt] = (f32x4){0.f, 0.f, 0.f, 0.f};
#pragma unroll
        for (int kk = 0; kk < 128; kk += 32) {
            bf16x8 a0 = ldfrag(&s_t1[(m0 + lr)      * PAD128 + kk + quad * 8]);
            bf16x8 a1 = ldfrag(&s_t1[(m0 + 16 + lr) * PAD128 + kk + quad * 8]);
#pragma unroll
            for (int nt = 0; nt < 8; ++nt) {
                bf16x8 b = ldfrag(mw2t + (nt * 16 + lr) * 128 + kk + quad * 8);
                accB[0][nt] = __builtin_amdgcn_mfma_f32_16x16x32_bf16(a0, b, accB[0][nt], 0, 0, 0);
                accB[1][nt] = __builtin_amdgcn_mfma_f32_16x16x32_bf16(a1, b, accB[1][nt], 0, 0, 0);
            }
        }
#pragma unroll
        for (int mt = 0; mt < 2; ++mt) {
            int r0 = m0 + mt * 16 + quad * 4;
            float c0 = s_cv[r0], c1 = s_cv[r0 + 1], c2 = s_cv[r0 + 2], c3 = s_cv[r0 + 3];
            u16* bp = &s_t1[r0 * PAD128 + lr];
#pragma unroll
            for (int nt = 0; nt < 8; ++nt) {
                int col = nt * 16;
                float bb = b2[col + lr];
                u32 p01 = pkbf((accB[mt][nt][0] + bb) * c0,
                               (accB[mt][nt][1] + bb) * c1);
                u32 p23 = pkbf((accB[mt][nt][2] + bb) * c2,
                               (accB[mt][nt][3] + bb) * c3);
                bp[col]              = (u16)p01;
                bp[col + PAD128]     = (u16)(p01 >> 16);
                bp[col + 2 * PAD128] = (u16)p23;
                bp[col + 3 * PAD128] = (u16)(p23 >> 16);
            }
        }
    }

    // Pass 2: receiver-sorted accumulate + flush. Loads batched 8-wide.
    {
        float a0 = 0.f, a1 = 0.f;
        int jc = s_rc[m0];
        const u16* sm = &s_t1[m0 * PAD128];
#pragma unroll
        for (int r0w = 0; r0w < 32; r0w += 8) {
            ushort2 mm[8];
            float2  xv[8];
            int     rj[8];
#pragma unroll
            for (int q = 0; q < 8; ++q) {
                int row = r0w + q;
                int e = s_ed[m0 + row];
                rj[q] = s_rc[m0 + row];
                int src = (e >= 0) ? (e >> 5) : 0;
                mm[q] = *(const ushort2*)&sm[row * PAD128 + lane * 2];
                xv[q] = *(const float2*)(xj + (size_t)src * 128 + lane * 2);
            }
#pragma unroll
            for (int q = 0; q < 8; ++q) {
                if (rj[q] != jc) {
                    if (jc >= 0) {
                        float* dst = agg + (size_t)jc * 128 + lane * 2;
                        atomicAdd(dst,     a0);
                        atomicAdd(dst + 1, a1);
                    }
                    jc = rj[q]; a0 = 0.f; a1 = 0.f;
                }
                a0 += bf2f(mm[q].x) * xv[q].x;   // pad rows: M == 0
                a1 += bf2f(mm[q].y) * xv[q].y;
            }
        }
        if (jc >= 0) {
            float* dst = agg + (size_t)jc * 128 + lane * 2;
            atomicAdd(dst,     a0);
            atomicAdd(dst + 1, a1);
        }
    }
}

// ---------------------------------------------------------------------------
// K6: output head — 16 atoms/block, LDS-tiled, one atomic per block.
// ---------------------------------------------------------------------------
__launch_bounds__(256)
__global__ void head_kernel(const float* __restrict__ h,
                            const float* __restrict__ ow1,
                            const float* __restrict__ ob1,
                            const float* __restrict__ ow2,
                            const float* __restrict__ ob2,
                            float* __restrict__ gsum) {
    __shared__ __align__(16) float s_w[128 * 64];
    __shared__ __align__(16) float s_h[16 * 132];
    __shared__ float s_sum;
    int tid = threadIdx.x;
    int a0 = blockIdx.x * 16;
    if (tid == 0) s_sum = 0.0f;
    {
        const float4* src = (const float4*)ow1;
        float4* dst = (float4*)s_w;
#pragma unroll
        for (int p = 0; p < 8; ++p) dst[tid + p * 256] = src[tid + p * 256];
    }
    {
        const float4* src = (const float4*)(h + (size_t)a0 * 128);
#pragma unroll
        for (int p = 0; p < 2; ++p) {
            int q = tid + p * 256;
            int r = q >> 5, c4 = (q & 31) * 4;
            *(float4*)&s_h[r * 132 + c4] = src[q];
        }
    }
    __syncthreads();
    int atom = tid >> 4, cg = tid & 15;
    const float* hr = &s_h[atom * 132];
    const float4* w4 = (const float4*)s_w;
    float4 acc = {0.f, 0.f, 0.f, 0.f};
#pragma unroll 8
    for (int f = 0; f < 128; ++f) {
        float hv = hr[f];
        float4 w = w4[f * 16 + cg];
        acc.x += hv * w.x; acc.y += hv * w.y;
        acc.z += hv * w.z; acc.w += hv * w.w;
    }
    int c0 = cg * 4;
    float v = silu_f(acc.x + ob1[c0 + 0]) * ow2[c0 + 0]
            + silu_f(acc.y + ob1[c0 + 1]) * ow2[c0 + 1]
            + silu_f(acc.z + ob1[c0 + 2]) * ow2[c0 + 2]
            + silu_f(acc.w + ob1[c0 + 3]) * ow2[c0 + 3];
    v += __shfl_xor(v, 1, 64);
    v += __shfl_xor(v, 2, 64);
    v += __shfl_xor(v, 4, 64);
    v += __shfl_xor(v, 8, 64);
    if ((tid & 15) == 0) atomicAdd(&s_sum, v + ob2[0]);
    __syncthreads();
    if (tid == 0) atomicAdd(&gsum[a0 >> 7], s_sum);
}

__global__ void finalize_kernel(const float* __restrict__ gsum, void* __restrict__ out,
                                const int* __restrict__ flag) {
    int t = threadIdx.x;
    if (*flag) ((float*)out)[t] = gsum[t];
    else       ((u16*)out)[t]   = f2bf(gsum[t]);
}

// ---------------------------------------------------------------------------
extern "C" void kernel_launch(void* const* d_in, const int* in_sizes, int n_in,
                              void* d_out, int out_size, void* d_ws, size_t ws_size,
                              hipStream_t stream) {
    const void* pos  = d_in[0];
    const int*  z    = (const int*)d_in[1];
    // d_in[2] = batch (implicit: graph = i >> 7)
    const void* emb  = d_in[3];
    const void* mw1  = d_in[4];
    const void* mb1  = d_in[5];
    const void* mw2  = d_in[6];
    const void* mb2  = d_in[7];
    const void* l1w  = d_in[8];
    const void* l1b  = d_in[9];
    const void* l2w  = d_in[10];
    const void* l2b  = d_in[11];
    const void* ow1  = d_in[12];
    const void* ob1  = d_in[13];
    const void* ow2  = d_in[14];
    const void* ob2  = d_in[15];

    char* ws = (char*)d_ws;
    const size_t KB = 1024, MB = 1048576;
    int*   w_flag  = (int*)  (ws);
    float* c_pos   = (float*)(ws + 4   * KB);
    float* c_emb   = (float*)(ws + 112 * KB);
    float* c_mb1   = (float*)(ws + 168 * KB);
    float* c_mb2   = (float*)(ws + 172 * KB);
    float* c_l1b   = (float*)(ws + 176 * KB);
    float* c_l2b   = (float*)(ws + 180 * KB);
    float* c_ow1   = (float*)(ws + 184 * KB);
    float* c_ob1   = (float*)(ws + 220 * KB);
    float* c_ow2   = (float*)(ws + 221 * KB);
    float* c_ob2   = (float*)(ws + 222 * KB);
    float* w_gsum  = (float*)(ws + 224 * KB);
    u16*   c_l1wt  = (u16*)  (ws + 256 * KB);
    u16*   c_l2wt  = (u16*)  (ws + 448 * KB);
    u16*   c_mw2t  = (u16*)  (ws + 640 * KB);
    u16*   c_mw1t  = (u16*)  (ws + 832 * KB);
    float* w_dist  = (float*)(ws + 1  * MB);
    float* w_cval  = (float*)(ws + 2  * MB);
    int*   rev_cnt = (int*)  (ws + 3  * MB);            // 32 KB
    int*   w_ne    = (int*)  (ws + 3  * MB + 32 * KB);  // edge count
    int*   w_roff  = (int*)  (ws + 3  * MB + 64 * KB);  // 32 KB
    int*   rev_e   = (int*)  (ws + 4  * MB);            // 4 MB
    float* w_h     = (float*)(ws + 8  * MB);
    float* w_xj    = (float*)(ws + 12 * MB);
    float* w_agg   = (float*)(ws + 16 * MB);
    int*   w_eord  = (int*)  (ws + 20 * MB);            // 1 MB
    int*   w_erecv = (int*)  (ws + 21 * MB);            // 1 MB

    hipMemsetAsync(rev_cnt, 0, NATOMS * sizeof(int), stream);
    hipMemsetAsync(w_gsum, 0, GRAPHS * sizeof(float), stream);

    probe_kernel<<<1, 256, 0, stream>>>((const u16*)emb, w_flag);

    IngestDesc dsc;
    const void* srcs[NARR] = {pos, emb, mb1, mb2, l1b, l2b, ow1, ob1, ow2, ob2};
    void* dsts[NARR] = {c_pos, c_emb, c_mb1, c_mb2, c_l1b, c_l2b, c_ow1, c_ob1,
                        c_ow2, c_ob2};
    int ns_[NARR] = {24576, 12800, 768, 768, 768, 768, 8192, 64, 64, 1};
    int total = 0;
    for (int a = 0; a < NARR; ++a) {
        dsc.src[a] = srcs[a]; dsc.dst[a] = dsts[a]; dsc.n[a] = ns_[a];
        total += ns_[a];
    }
    ingest_kernel<<<(total + 255) / 256, 256, 0, stream>>>(dsc, w_flag, total);
    prep_weights<<<1344, 256, 0, stream>>>(l1w, l2w, mw2, mw1,
                                           c_l1wt, c_l2wt, c_mw2t, c_mw1t, w_flag);

    build_graph_kernel<<<NATOMS / 4, 256, 0, stream>>>(c_pos, w_dist, w_cval,
                                                       rev_cnt, rev_e);
    scan_offsets<<<1, 256, 0, stream>>>(rev_cnt, w_roff, w_ne);
    fill_eord<<<NATOMS / 256, 256, 0, stream>>>(rev_cnt, rev_e, w_roff,
                                                w_eord, w_erecv);
    embed_kernel<<<NATOMS, HID, 0, stream>>>(z, c_emb, w_h);

    for (int l = 0; l < LAYERS; ++l) {
        gemm_mfma<0, 0><<<NATOMS / 32, 256, 0, stream>>>(
            w_h, c_l1wt + (size_t)l * 16384, c_l1b + (size_t)l * 128, w_xj);
        hipMemsetAsync(w_agg, 0, (size_t)NATOMS * HID * sizeof(float), stream);
        wagg_kernel<<<2048, 256, 0, stream>>>(
            w_dist, w_cval, w_xj,
            c_mw1t + (size_t)l * 8192, c_mw2t + (size_t)l * 16384,
            c_mb1 + (size_t)l * 128, c_mb2 + (size_t)l * 128,
            w_eord, w_erecv, w_ne, w_agg);
        gemm_mfma<1, 1><<<NATOMS / 32, 256, 0, stream>>>(
            w_agg, c_l2wt + (size_t)l * 16384, c_l2b + (size_t)l * 128, w_h);
    }

    head_kernel<<<NATOMS / 16, 256, 0, stream>>>(w_h, c_ow1, c_ob1, c_ow2, c_ob2,
                                                 w_gsum);
    finalize_kernel<<<1, GRAPHS, 0, stream>>>(w_gsum, (void*)d_out, w_flag);
}

// Round 9
// 512.237 us; speedup vs baseline: 1.9120x; 1.3559x over previous
//
#include <hip/hip_runtime.h>
#include <math.h>

typedef unsigned short u16;
typedef unsigned int   u32;
typedef unsigned long long u64;

#define NATOMS 8192
#define GRAPHS 64
#define APG    128
#define KNN    32
#define NGAUSS 50
#define HID    128
#define LAYERS 6
#define PAD128 136
#define NTAB   2048

typedef __attribute__((ext_vector_type(8))) short bf16x8;
typedef __attribute__((ext_vector_type(4))) float f32x4;

__device__ __forceinline__ float bf2f(u16 v) {
    return __uint_as_float(((u32)v) << 16);
}
__device__ __forceinline__ u16 f2bf(float f) {
    u32 u = __float_as_uint(f);
    u32 lsb = (u >> 16) & 1u;
    u += 0x7fffu + lsb;
    return (u16)(u >> 16);
}
__device__ __forceinline__ u32 pkbf(float lo, float hi) {
#if __has_builtin(__builtin_amdgcn_cvt_pk_bf16_f32)
    auto r = __builtin_amdgcn_cvt_pk_bf16_f32(lo, hi);
    u32 u; __builtin_memcpy(&u, &r, 4); return u;
#else
    return (u32)f2bf(lo) | ((u32)f2bf(hi) << 16);
#endif
}
__device__ __forceinline__ float silu_f(float x) {
    return x * __builtin_amdgcn_rcpf(1.0f + __expf(-x));
}
__device__ __forceinline__ bf16x8 ldfrag(const u16* p) {
    return *(const bf16x8*)__builtin_assume_aligned(p, 16);
}
__device__ __forceinline__ u64 shfl_xor_u64(u64 v, int mask) {
    u32 lo = (u32)v, hi = (u32)(v >> 32);
    lo = (u32)__shfl_xor((int)lo, mask, 64);
    hi = (u32)__shfl_xor((int)hi, mask, 64);
    return ((u64)hi << 32) | lo;
}

// ---------------------------------------------------------------------------
// K0: dtype probe (fp32 vs bf16 float inputs)
// ---------------------------------------------------------------------------
__global__ void probe_kernel(const u16* __restrict__ raw, int* __restrict__ flag) {
    __shared__ int s;
    int t = threadIdx.x;
    if (t == 0) s = 0;
    __syncthreads();
    float x = bf2f(raw[2 * t]);
    if (!(fabsf(x) < 1000.0f)) atomicOr(&s, 1);
    __syncthreads();
    if (t == 0) *flag = s;
}

// ---------------------------------------------------------------------------
// K0b: ingest fp32-canonical copies (incl. mw1/mw2 full fp32 for the table).
// ---------------------------------------------------------------------------
#define NARR 12
struct IngestDesc {
    const void* src[NARR];
    void*       dst[NARR];
    int         n[NARR];
};

__global__ void ingest_kernel(IngestDesc d, const int* __restrict__ flag, int total) {
    int gid = blockIdx.x * blockDim.x + threadIdx.x;
    if (gid >= total) return;
    int a = 0, off = gid;
    while (off >= d.n[a]) { off -= d.n[a]; ++a; }
    bool f32in = (*flag != 0);
    float v = f32in ? ((const float*)d.src[a])[off]
                    : bf2f(((const u16*)d.src[a])[off]);
    ((float*)d.dst[a])[off] = v;
}

// ---------------------------------------------------------------------------
// K0c: weight prep — transpose l1w/l2w to [n][k] bf16 for MFMA B-operands.
// ---------------------------------------------------------------------------
__global__ void prep_weights(const void* __restrict__ l1w, const void* __restrict__ l2w,
                             u16* __restrict__ l1wt, u16* __restrict__ l2wt,
                             const int* __restrict__ flag) {
    int gid = blockIdx.x * blockDim.x + threadIdx.x;
    if (gid >= 2 * 98304) return;
    bool f32in = (*flag != 0);
    int seg = gid / 98304;
    int t = gid % 98304;
    int l = t >> 14;
    int n = (t >> 7) & 127;
    int k = t & 127;
    const void* src = (seg == 0) ? l1w : l2w;
    u16* dst = (seg == 0) ? l1wt : l2wt;
    int si = l * 16384 + k * 128 + n;
    float v = f32in ? ((const float*)src)[si] : bf2f(((const u16*)src)[si]);
    dst[t] = f2bf(v);
}

// ---------------------------------------------------------------------------
// K1: graph build, one WAVE per center atom. u64 (d2,j) keys, butterfly min
// x32 == jax.lax.top_k order. Builds reverse adjacency (cv>0 edges only).
// ---------------------------------------------------------------------------
__launch_bounds__(256)
__global__ void build_graph_kernel(const float* __restrict__ pos,
                                   float* __restrict__ dist,
                                   int* __restrict__ rev_cnt,
                                   int* __restrict__ rev_e) {
    int wv = threadIdx.x >> 6, lane = threadIdx.x & 63;
    int t = blockIdx.x * 4 + wv;
    int tl = t & 127;
    int base = t & ~127;
    float cx = pos[t * 3 + 0];
    float cy = pos[t * 3 + 1];
    float cz = pos[t * 3 + 2];
    u64 key[2];
#pragma unroll
    for (int c = 0; c < 2; ++c) {
        int j = lane + c * 64;
        float jx = pos[(base + j) * 3 + 0];
        float jy = pos[(base + j) * 3 + 1];
        float jz = pos[(base + j) * 3 + 2];
        float dx = __fsub_rn(cx, jx);
        float dy = __fsub_rn(cy, jy);
        float dz = __fsub_rn(cz, jz);
        float d2 = __fadd_rn(__fadd_rn(__fmul_rn(dx, dx), __fmul_rn(dy, dy)),
                             __fmul_rn(dz, dz));
        bool valid = (j != tl) && (d2 < 100.0f);
        key[c] = valid ? ((((u64)__float_as_uint(d2)) << 32) | (u32)j) : ~0ULL;
    }
    for (int k = 0; k < KNN; ++k) {
        u64 m = key[0] < key[1] ? key[0] : key[1];
#pragma unroll
        for (int off = 32; off > 0; off >>= 1) {
            u64 o = shfl_xor_u64(m, off);
            if (o < m) m = o;
        }
        int e = t * KNN + k;
        if (m == ~0ULL) {
            if (lane == 0) dist[e] = 1.0f;
        } else {
            if (key[0] == m) key[0] = ~0ULL;
            if (key[1] == m) key[1] = ~0ULL;
            if (lane == (int)(m & 63)) {
                float d2 = __uint_as_float((u32)(m >> 32));
                float d = __fsqrt_rn(d2);
                dist[e] = d;
                if (d < 10.0f) {       // cv>0 <=> valid edge (d<10 and finite)
                    int j = base + (int)(m & 0xffffffffu);
                    int p = atomicAdd(&rev_cnt[j], 1);
                    rev_e[(size_t)j * 128 + p] = e;
                }
            }
        }
    }
}

// ---------------------------------------------------------------------------
// K1b: per-edge prep: (src, table index i0, frac) for each rev-list entry.
// One thread per (receiver, slot). Runs once per forward.
// ---------------------------------------------------------------------------
__global__ void edge_prep(const int* __restrict__ rev_cnt,
                          const int* __restrict__ rev_e,
                          const float* __restrict__ dist,
                          int2* __restrict__ rev_si,
                          float* __restrict__ rev_fr) {
    int gid = blockIdx.x * 256 + threadIdx.x;
    int j = gid >> 7, k = gid & 127;
    if (k >= rev_cnt[j]) return;
    int e = rev_e[(size_t)j * 128 + k];
    float d = dist[e];
    float u = d * ((float)(NTAB - 1) / 10.0f);
    int i0 = (int)u;
    if (i0 > NTAB - 2) i0 = NTAB - 2;
    rev_si[gid] = make_int2(e >> 5, i0);
    rev_fr[gid] = u - (float)i0;
}

// ---------------------------------------------------------------------------
// K2: embedding gather
// ---------------------------------------------------------------------------
__global__ void embed_kernel(const int* __restrict__ z,
                             const float* __restrict__ emb,
                             float* __restrict__ h) {
    int i = blockIdx.x, t = threadIdx.x;
    h[(size_t)i * HID + t] = emb[(size_t)z[i] * HID + t];
}

// ---------------------------------------------------------------------------
// K3: dense MFMA GEMM (unchanged, verified).
// ---------------------------------------------------------------------------
template <int MODE, int SPLIT>
__launch_bounds__(256)
__global__ void gemm_mfma(const float* __restrict__ A,
                          const u16* __restrict__ Bt,
                          const float* __restrict__ bias,
                          float* __restrict__ O) {
    __shared__ u16 s_ahi[32 * PAD128];
    __shared__ u16 s_alo[SPLIT ? 32 * PAD128 : 2];
    __shared__ u16 s_b[128 * PAD128];
    __shared__ float s_bias[128];
    int tid = threadIdx.x;
    int row0 = blockIdx.x * 32;
    {
        const float4* src = (const float4*)(A + (size_t)row0 * 128);
        for (int p = 0; p < 4; ++p) {
            int q = tid + p * 256;
            int r = q >> 5, k4 = (q & 31) * 4;
            float4 v = src[q];
            u32 h0 = pkbf(v.x, v.y), h1 = pkbf(v.z, v.w);
            u32* hd = (u32*)&s_ahi[r * PAD128 + k4];
            hd[0] = h0; hd[1] = h1;
            if (SPLIT) {
                u32 l0 = pkbf(v.x - bf2f((u16)h0), v.y - bf2f((u16)(h0 >> 16)));
                u32 l1 = pkbf(v.z - bf2f((u16)h1), v.w - bf2f((u16)(h1 >> 16)));
                u32* ld = (u32*)&s_alo[r * PAD128 + k4];
                ld[0] = l0; ld[1] = l1;
            }
        }
    }
    {
        const uint4* src = (const uint4*)Bt;
        for (int p = 0; p < 8; ++p) {
            int q = tid + p * 256;
            int r = q >> 4, c8 = (q & 15) * 8;
            *(uint4*)&s_b[r * PAD128 + c8] = src[q];
        }
    }
    if (tid < 128) s_bias[tid] = bias[tid];
    __syncthreads();

    int wv = tid >> 6, lane = tid & 63;
    int quad = lane >> 4, lr = lane & 15;
    int n0 = wv * 32;
    f32x4 acc[2][2];
#pragma unroll
    for (int mt = 0; mt < 2; ++mt)
#pragma unroll
        for (int nt = 0; nt < 2; ++nt) acc[mt][nt] = (f32x4){0.f, 0.f, 0.f, 0.f};
#pragma unroll
    for (int kk = 0; kk < 128; kk += 32) {
        bf16x8 ah0 = ldfrag(&s_ahi[(lr)      * PAD128 + kk + quad * 8]);
        bf16x8 ah1 = ldfrag(&s_ahi[(16 + lr) * PAD128 + kk + quad * 8]);
#pragma unroll
        for (int nt = 0; nt < 2; ++nt) {
            bf16x8 b = ldfrag(&s_b[(n0 + nt * 16 + lr) * PAD128 + kk + quad * 8]);
            acc[0][nt] = __builtin_amdgcn_mfma_f32_16x16x32_bf16(ah0, b, acc[0][nt], 0, 0, 0);
            acc[1][nt] = __builtin_amdgcn_mfma_f32_16x16x32_bf16(ah1, b, acc[1][nt], 0, 0, 0);
        }
        if (SPLIT) {
            bf16x8 al0 = ldfrag(&s_alo[(lr)      * PAD128 + kk + quad * 8]);
            bf16x8 al1 = ldfrag(&s_alo[(16 + lr) * PAD128 + kk + quad * 8]);
#pragma unroll
            for (int nt = 0; nt < 2; ++nt) {
                bf16x8 b = ldfrag(&s_b[(n0 + nt * 16 + lr) * PAD128 + kk + quad * 8]);
                acc[0][nt] = __builtin_amdgcn_mfma_f32_16x16x32_bf16(al0, b, acc[0][nt], 0, 0, 0);
                acc[1][nt] = __builtin_amdgcn_mfma_f32_16x16x32_bf16(al1, b, acc[1][nt], 0, 0, 0);
            }
        }
    }
#pragma unroll
    for (int mt = 0; mt < 2; ++mt)
#pragma unroll
        for (int nt = 0; nt < 2; ++nt)
#pragma unroll
            for (int r = 0; r < 4; ++r) {
                int grow = row0 + mt * 16 + quad * 4 + r;
                int col = n0 + nt * 16 + lr;
                float v = acc[mt][nt][r] + s_bias[col];
                size_t off = (size_t)grow * 128 + col;
                if (MODE == 0) O[off] = v;
                else           O[off] += silu_f(v);
            }
}

// ---------------------------------------------------------------------------
// K4a: filter table. Vtab[t][c] = cv(d_t) * (silu(rbf(d_t)@mw1+b1)@mw2+b2)[c]
// d_t = t*10/(NTAB-1). Full fp32 (more accurate than the old bf16 MFMA path).
// One block computes 2 rows; 1024 blocks.
// ---------------------------------------------------------------------------
__launch_bounds__(256)
__global__ void vtab_kernel(const float* __restrict__ mw1f,   // [50][128]
                            const float* __restrict__ mw2f,   // [128][128]
                            const float* __restrict__ b1,
                            const float* __restrict__ b2,
                            float* __restrict__ Vtab) {       // [NTAB][128]
    __shared__ float s_rbf[2][64];
    __shared__ float s_t1[2][128];
    int tid = threadIdx.x;
    int rw = tid >> 7, col = tid & 127;
    int row = blockIdx.x * 2 + rw;
    float d = (float)row * (10.0f / (float)(NTAB - 1));
    if (col < NGAUSS) {
        float tt = (d - (10.0f / 49.0f) * (float)col) * (49.0f / 10.0f);
        s_rbf[rw][col] = __expf(-0.5f * tt * tt);
    }
    __syncthreads();
    float a = b1[col];
#pragma unroll 10
    for (int g = 0; g < NGAUSS; ++g) a += s_rbf[rw][g] * mw1f[g * 128 + col];
    s_t1[rw][col] = silu_f(a);
    __syncthreads();
    float v = b2[col];
#pragma unroll 8
    for (int f = 0; f < 128; ++f) v += s_t1[rw][f] * mw2f[f * 128 + col];
    float cv = 0.5f * (cosf(d * 3.14159265f / 10.0f) + 1.0f);
    Vtab[row * 128 + col] = v * cv;
}

// ---------------------------------------------------------------------------
// K4b: aggregate. One wave per receiver: agg[j] = sum_e lerp(Vtab,d_e)*xj[src].
// (src,i0,frac) precomputed; table+xj L2-hot; plain stores, no atomics.
// ---------------------------------------------------------------------------
__launch_bounds__(256)
__global__ void agg_kernel(const int* __restrict__ rev_cnt,
                           const int2* __restrict__ rev_si,
                           const float* __restrict__ rev_fr,
                           const float* __restrict__ Vtab,
                           const float* __restrict__ xj,
                           float* __restrict__ agg) {
    int j = blockIdx.x * 4 + (threadIdx.x >> 6);
    int lane = threadIdx.x & 63;
    int deg = rev_cnt[j];
    const int2*  si = rev_si + (size_t)j * 128;
    const float* fr = rev_fr + (size_t)j * 128;
    int c2 = lane * 2;
    float a0 = 0.f, a1 = 0.f, b0 = 0.f, b1 = 0.f;
    int it = 0;
    for (; it + 2 <= deg; it += 2) {
        int2 s0 = si[it], s1 = si[it + 1];
        float f0 = fr[it], f1 = fr[it + 1];
        float2 va0 = *(const float2*)(Vtab + s0.y * 128 + c2);
        float2 vb0 = *(const float2*)(Vtab + s0.y * 128 + 128 + c2);
        float2 xv0 = *(const float2*)(xj + (size_t)s0.x * 128 + c2);
        float2 va1 = *(const float2*)(Vtab + s1.y * 128 + c2);
        float2 vb1 = *(const float2*)(Vtab + s1.y * 128 + 128 + c2);
        float2 xv1 = *(const float2*)(xj + (size_t)s1.x * 128 + c2);
        a0 += (va0.x + (vb0.x - va0.x) * f0) * xv0.x;
        a1 += (va0.y + (vb0.y - va0.y) * f0) * xv0.y;
        b0 += (va1.x + (vb1.x - va1.x) * f1) * xv1.x;
        b1 += (va1.y + (vb1.y - va1.y) * f1) * xv1.y;
    }
    if (it < deg) {
        int2 s0 = si[it];
        float f0 = fr[it];
        float2 va0 = *(const float2*)(Vtab + s0.y * 128 + c2);
        float2 vb0 = *(const float2*)(Vtab + s0.y * 128 + 128 + c2);
        float2 xv0 = *(const float2*)(xj + (size_t)s0.x * 128 + c2);
        a0 += (va0.x + (vb0.x - va0.x) * f0) * xv0.x;
        a1 += (va0.y + (vb0.y - va0.y) * f0) * xv0.y;
    }
    float2 r; r.x = a0 + b0; r.y = a1 + b1;
    *(float2*)(agg + (size_t)j * 128 + c2) = r;
}

// ---------------------------------------------------------------------------
// K6: output head — 16 atoms/block, LDS-tiled, one atomic per block.
// ---------------------------------------------------------------------------
__launch_bounds__(256)
__global__ void head_kernel(const float* __restrict__ h,
                            const float* __restrict__ ow1,
                            const float* __restrict__ ob1,
                            const float* __restrict__ ow2,
                            const float* __restrict__ ob2,
                            float* __restrict__ gsum) {
    __shared__ __align__(16) float s_w[128 * 64];
    __shared__ __align__(16) float s_h[16 * 132];
    __shared__ float s_sum;
    int tid = threadIdx.x;
    int a0 = blockIdx.x * 16;
    if (tid == 0) s_sum = 0.0f;
    {
        const float4* src = (const float4*)ow1;
        float4* dst = (float4*)s_w;
#pragma unroll
        for (int p = 0; p < 8; ++p) dst[tid + p * 256] = src[tid + p * 256];
    }
    {
        const float4* src = (const float4*)(h + (size_t)a0 * 128);
#pragma unroll
        for (int p = 0; p < 2; ++p) {
            int q = tid + p * 256;
            int r = q >> 5, c4 = (q & 31) * 4;
            *(float4*)&s_h[r * 132 + c4] = src[q];
        }
    }
    __syncthreads();
    int atom = tid >> 4, cg = tid & 15;
    const float* hr = &s_h[atom * 132];
    const float4* w4 = (const float4*)s_w;
    float4 acc = {0.f, 0.f, 0.f, 0.f};
#pragma unroll 8
    for (int f = 0; f < 128; ++f) {
        float hv = hr[f];
        float4 w = w4[f * 16 + cg];
        acc.x += hv * w.x; acc.y += hv * w.y;
        acc.z += hv * w.z; acc.w += hv * w.w;
    }
    int c0 = cg * 4;
    float v = silu_f(acc.x + ob1[c0 + 0]) * ow2[c0 + 0]
            + silu_f(acc.y + ob1[c0 + 1]) * ow2[c0 + 1]
            + silu_f(acc.z + ob1[c0 + 2]) * ow2[c0 + 2]
            + silu_f(acc.w + ob1[c0 + 3]) * ow2[c0 + 3];
    v += __shfl_xor(v, 1, 64);
    v += __shfl_xor(v, 2, 64);
    v += __shfl_xor(v, 4, 64);
    v += __shfl_xor(v, 8, 64);
    if ((tid & 15) == 0) atomicAdd(&s_sum, v + ob2[0]);
    __syncthreads();
    if (tid == 0) atomicAdd(&gsum[a0 >> 7], s_sum);
}

__global__ void finalize_kernel(const float* __restrict__ gsum, void* __restrict__ out,
                                const int* __restrict__ flag) {
    int t = threadIdx.x;
    if (*flag) ((float*)out)[t] = gsum[t];
    else       ((u16*)out)[t]   = f2bf(gsum[t]);
}

// ---------------------------------------------------------------------------
extern "C" void kernel_launch(void* const* d_in, const int* in_sizes, int n_in,
                              void* d_out, int out_size, void* d_ws, size_t ws_size,
                              hipStream_t stream) {
    const void* pos  = d_in[0];
    const int*  z    = (const int*)d_in[1];
    // d_in[2] = batch (implicit: graph = i >> 7)
    const void* emb  = d_in[3];
    const void* mw1  = d_in[4];
    const void* mb1  = d_in[5];
    const void* mw2  = d_in[6];
    const void* mb2  = d_in[7];
    const void* l1w  = d_in[8];
    const void* l1b  = d_in[9];
    const void* l2w  = d_in[10];
    const void* l2b  = d_in[11];
    const void* ow1  = d_in[12];
    const void* ob1  = d_in[13];
    const void* ow2  = d_in[14];
    const void* ob2  = d_in[15];

    char* ws = (char*)d_ws;
    const size_t KB = 1024, MB = 1048576;
    int*   w_flag  = (int*)  (ws);
    float* c_pos   = (float*)(ws + 4   * KB);
    float* c_emb   = (float*)(ws + 112 * KB);
    float* c_mb1   = (float*)(ws + 168 * KB);
    float* c_mb2   = (float*)(ws + 176 * KB);
    float* c_l1b   = (float*)(ws + 184 * KB);
    float* c_l2b   = (float*)(ws + 192 * KB);
    float* c_ow1   = (float*)(ws + 200 * KB);
    float* c_ob1   = (float*)(ws + 236 * KB);
    float* c_ow2   = (float*)(ws + 240 * KB);
    float* c_ob2   = (float*)(ws + 244 * KB);
    float* w_gsum  = (float*)(ws + 248 * KB);
    u16*   c_l1wt  = (u16*)  (ws + 256 * KB);   // 192 KB
    u16*   c_l2wt  = (u16*)  (ws + 448 * KB);   // 192 KB
    float* c_mw1f  = (float*)(ws + 640 * KB);   // 150 KB fp32
    float* c_mw2f  = (float*)(ws + 800 * KB);   // 384 KB fp32
    float* w_dist  = (float*)(ws + 2  * MB);    // 1 MB
    int*   rev_cnt = (int*)  (ws + 4  * MB);    // 32 KB
    int*   rev_e   = (int*)  (ws + 5  * MB);    // 4 MB
    float* w_h     = (float*)(ws + 9  * MB);
    float* w_xj    = (float*)(ws + 13 * MB);
    float* w_agg   = (float*)(ws + 17 * MB);
    float* w_vtab  = (float*)(ws + 21 * MB);    // 1 MB
    int2*  rev_si  = (int2*) (ws + 22 * MB);    // 8 MB
    float* rev_fr  = (float*)(ws + 30 * MB);    // 4 MB

    hipMemsetAsync(rev_cnt, 0, NATOMS * sizeof(int), stream);
    hipMemsetAsync(w_gsum, 0, GRAPHS * sizeof(float), stream);

    probe_kernel<<<1, 256, 0, stream>>>((const u16*)emb, w_flag);

    IngestDesc dsc;
    const void* srcs[NARR] = {pos, emb, mb1, mb2, l1b, l2b, ow1, ob1, ow2, ob2,
                              mw1, mw2};
    void* dsts[NARR] = {c_pos, c_emb, c_mb1, c_mb2, c_l1b, c_l2b, c_ow1, c_ob1,
                        c_ow2, c_ob2, c_mw1f, c_mw2f};
    int ns_[NARR] = {24576, 12800, 768, 768, 768, 768, 8192, 64, 64, 1,
                     38400, 98304};
    int total = 0;
    for (int a = 0; a < NARR; ++a) {
        dsc.src[a] = srcs[a]; dsc.dst[a] = dsts[a]; dsc.n[a] = ns_[a];
        total += ns_[a];
    }
    ingest_kernel<<<(total + 255) / 256, 256, 0, stream>>>(dsc, w_flag, total);
    prep_weights<<<768, 256, 0, stream>>>(l1w, l2w, c_l1wt, c_l2wt, w_flag);

    build_graph_kernel<<<NATOMS / 4, 256, 0, stream>>>(c_pos, w_dist,
                                                       rev_cnt, rev_e);
    edge_prep<<<NATOMS * 128 / 256, 256, 0, stream>>>(rev_cnt, rev_e, w_dist,
                                                      rev_si, rev_fr);
    embed_kernel<<<NATOMS, HID, 0, stream>>>(z, c_emb, w_h);

    for (int l = 0; l < LAYERS; ++l) {
        gemm_mfma<0, 0><<<NATOMS / 32, 256, 0, stream>>>(
            w_h, c_l1wt + (size_t)l * 16384, c_l1b + (size_t)l * 128, w_xj);
        vtab_kernel<<<NTAB / 2, 256, 0, stream>>>(
            c_mw1f + (size_t)l * 6400, c_mw2f + (size_t)l * 16384,
            c_mb1 + (size_t)l * 128, c_mb2 + (size_t)l * 128, w_vtab);
        agg_kernel<<<NATOMS / 4, 256, 0, stream>>>(
            rev_cnt, rev_si, rev_fr, w_vtab, w_xj, w_agg);
        gemm_mfma<1, 1><<<NATOMS / 32, 256, 0, stream>>>(
            w_agg, c_l2wt + (size_t)l * 16384, c_l2b + (size_t)l * 128, w_h);
    }

    head_kernel<<<NATOMS / 16, 256, 0, stream>>>(w_h, c_ow1, c_ob1, c_ow2, c_ob2,
                                                 w_gsum);
    finalize_kernel<<<1, GRAPHS, 0, stream>>>(w_gsum, (void*)d_out, w_flag);
}

// Round 10
// 401.440 us; speedup vs baseline: 2.4398x; 1.2760x over previous
//
#include <hip/hip_runtime.h>
#include <math.h>

typedef unsigned short u16;
typedef unsigned int   u32;
typedef unsigned long long u64;

#define NATOMS 8192
#define GRAPHS 64
#define APG    128
#define KNN    32
#define NGAUSS 50
#define HID    128
#define LAYERS 6
#define PAD128 136
#define NTAB   2048

typedef __attribute__((ext_vector_type(8))) short bf16x8;
typedef __attribute__((ext_vector_type(4))) float f32x4;

__device__ __forceinline__ float bf2f(u16 v) {
    return __uint_as_float(((u32)v) << 16);
}
__device__ __forceinline__ u16 f2bf(float f) {
    u32 u = __float_as_uint(f);
    u32 lsb = (u >> 16) & 1u;
    u += 0x7fffu + lsb;
    return (u16)(u >> 16);
}
__device__ __forceinline__ u32 pkbf(float lo, float hi) {
#if __has_builtin(__builtin_amdgcn_cvt_pk_bf16_f32)
    auto r = __builtin_amdgcn_cvt_pk_bf16_f32(lo, hi);
    u32 u; __builtin_memcpy(&u, &r, 4); return u;
#else
    return (u32)f2bf(lo) | ((u32)f2bf(hi) << 16);
#endif
}
__device__ __forceinline__ float silu_f(float x) {
    return x * __builtin_amdgcn_rcpf(1.0f + __expf(-x));
}
__device__ __forceinline__ bf16x8 ldfrag(const u16* p) {
    return *(const bf16x8*)__builtin_assume_aligned(p, 16);
}
__device__ __forceinline__ u64 shfl_xor_u64(u64 v, int mask) {
    u32 lo = (u32)v, hi = (u32)(v >> 32);
    lo = (u32)__shfl_xor((int)lo, mask, 64);
    hi = (u32)__shfl_xor((int)hi, mask, 64);
    return ((u64)hi << 32) | lo;
}

// ---------------------------------------------------------------------------
// K0: dtype probe (fp32 vs bf16 float inputs)
// ---------------------------------------------------------------------------
__global__ void probe_kernel(const u16* __restrict__ raw, int* __restrict__ flag) {
    __shared__ int s;
    int t = threadIdx.x;
    if (t == 0) s = 0;
    __syncthreads();
    float x = bf2f(raw[2 * t]);
    if (!(fabsf(x) < 1000.0f)) atomicOr(&s, 1);
    __syncthreads();
    if (t == 0) *flag = s;
}

// ---------------------------------------------------------------------------
// K0b: ingest fp32-canonical copies (incl. mw1/mw2 full fp32 for the table).
// ---------------------------------------------------------------------------
#define NARR 12
struct IngestDesc {
    const void* src[NARR];
    void*       dst[NARR];
    int         n[NARR];
};

__global__ void ingest_kernel(IngestDesc d, const int* __restrict__ flag, int total) {
    int gid = blockIdx.x * blockDim.x + threadIdx.x;
    if (gid >= total) return;
    int a = 0, off = gid;
    while (off >= d.n[a]) { off -= d.n[a]; ++a; }
    bool f32in = (*flag != 0);
    float v = f32in ? ((const float*)d.src[a])[off]
                    : bf2f(((const u16*)d.src[a])[off]);
    ((float*)d.dst[a])[off] = v;
}

// ---------------------------------------------------------------------------
// K0c: weight prep — transpose l1w/l2w to [n][k] bf16 for MFMA B-operands.
// ---------------------------------------------------------------------------
__global__ void prep_weights(const void* __restrict__ l1w, const void* __restrict__ l2w,
                             u16* __restrict__ l1wt, u16* __restrict__ l2wt,
                             const int* __restrict__ flag) {
    int gid = blockIdx.x * blockDim.x + threadIdx.x;
    if (gid >= 2 * 98304) return;
    bool f32in = (*flag != 0);
    int seg = gid / 98304;
    int t = gid % 98304;
    int l = t >> 14;
    int n = (t >> 7) & 127;
    int k = t & 127;
    const void* src = (seg == 0) ? l1w : l2w;
    u16* dst = (seg == 0) ? l1wt : l2wt;
    int si = l * 16384 + k * 128 + n;
    float v = f32in ? ((const float*)src)[si] : bf2f(((const u16*)src)[si]);
    dst[t] = f2bf(v);
}

// ---------------------------------------------------------------------------
// K1: graph build, one WAVE per center atom. 128 u64 (d2,j) keys (2/lane),
// full bitonic sort (28 stages, ~54 shfls) — ascending order == jax.lax.top_k
// tie order; lanes 0..31 of reg0 then hold the 32 nearest in order.
// ---------------------------------------------------------------------------
__launch_bounds__(256)
__global__ void build_graph_kernel(const float* __restrict__ pos,
                                   float* __restrict__ dist,
                                   int* __restrict__ rev_cnt,
                                   int* __restrict__ rev_e) {
    int wv = threadIdx.x >> 6, lane = threadIdx.x & 63;
    int t = blockIdx.x * 4 + wv;
    int tl = t & 127;
    int base = t & ~127;
    float cx = pos[t * 3 + 0];
    float cy = pos[t * 3 + 1];
    float cz = pos[t * 3 + 2];
    u64 key[2];
#pragma unroll
    for (int c = 0; c < 2; ++c) {
        int j = lane + c * 64;
        float jx = pos[(base + j) * 3 + 0];
        float jy = pos[(base + j) * 3 + 1];
        float jz = pos[(base + j) * 3 + 2];
        float dx = __fsub_rn(cx, jx);
        float dy = __fsub_rn(cy, jy);
        float dz = __fsub_rn(cz, jz);
        float d2 = __fadd_rn(__fadd_rn(__fmul_rn(dx, dx), __fmul_rn(dy, dy)),
                             __fmul_rn(dz, dz));
        bool valid = (j != tl) && (d2 < 100.0f);
        key[c] = valid ? ((((u64)__float_as_uint(d2)) << 32) | (u32)j) : ~0ULL;
    }
    // bitonic sort, element index ii = reg*64 + lane, ascending
#pragma unroll
    for (int k = 2; k <= 128; k <<= 1) {
#pragma unroll
        for (int j = k >> 1; j > 0; j >>= 1) {
            if (j == 64) {
                // only at k=128: dir ascending everywhere -> reg0=min, reg1=max
                u64 lo = key[0] < key[1] ? key[0] : key[1];
                u64 hi = key[0] < key[1] ? key[1] : key[0];
                key[0] = lo; key[1] = hi;
            } else {
#pragma unroll
                for (int r = 0; r < 2; ++r) {
                    u64 o = shfl_xor_u64(key[r], j);
                    u32 ii = (u32)(r * 64 + lane);
                    bool dir = ((ii & (u32)k) == 0);
                    bool lower = ((ii & (u32)j) == 0);
                    bool keep_min = (dir == lower);
                    bool less = key[r] < o;
                    key[r] = (less == keep_min) ? key[r] : o;
                }
            }
        }
    }
    if (lane < KNN) {
        u64 m = key[0];
        int e = t * KNN + lane;
        if (m == ~0ULL) {
            dist[e] = 1.0f;
        } else {
            float d2 = __uint_as_float((u32)(m >> 32));
            float d = __fsqrt_rn(d2);
            dist[e] = d;
            if (d < 10.0f) {
                int jn = base + (int)(m & 0xffffffffu);
                int p = atomicAdd(&rev_cnt[jn], 1);
                rev_e[(size_t)jn * 128 + p] = e;
            }
        }
    }
}

// ---------------------------------------------------------------------------
// K1b: per-edge prep: (src, table index i0, frac) for each rev-list entry.
// ---------------------------------------------------------------------------
__global__ void edge_prep(const int* __restrict__ rev_cnt,
                          const int* __restrict__ rev_e,
                          const float* __restrict__ dist,
                          int2* __restrict__ rev_si,
                          float* __restrict__ rev_fr) {
    int gid = blockIdx.x * 256 + threadIdx.x;
    int j = gid >> 7, k = gid & 127;
    if (k >= rev_cnt[j]) return;
    int e = rev_e[(size_t)j * 128 + k];
    float d = dist[e];
    float u = d * ((float)(NTAB - 1) / 10.0f);
    int i0 = (int)u;
    if (i0 > NTAB - 2) i0 = NTAB - 2;
    rev_si[gid] = make_int2(e >> 5, i0);
    rev_fr[gid] = u - (float)i0;
}

// ---------------------------------------------------------------------------
// K2: embedding gather
// ---------------------------------------------------------------------------
__global__ void embed_kernel(const int* __restrict__ z,
                             const float* __restrict__ emb,
                             float* __restrict__ h) {
    int i = blockIdx.x, t = threadIdx.x;
    h[(size_t)i * HID + t] = emb[(size_t)z[i] * HID + t];
}

// ---------------------------------------------------------------------------
// K3: dense MFMA GEMM (unchanged, verified).
// ---------------------------------------------------------------------------
template <int MODE, int SPLIT>
__launch_bounds__(256)
__global__ void gemm_mfma(const float* __restrict__ A,
                          const u16* __restrict__ Bt,
                          const float* __restrict__ bias,
                          float* __restrict__ O) {
    __shared__ u16 s_ahi[32 * PAD128];
    __shared__ u16 s_alo[SPLIT ? 32 * PAD128 : 2];
    __shared__ u16 s_b[128 * PAD128];
    __shared__ float s_bias[128];
    int tid = threadIdx.x;
    int row0 = blockIdx.x * 32;
    {
        const float4* src = (const float4*)(A + (size_t)row0 * 128);
        for (int p = 0; p < 4; ++p) {
            int q = tid + p * 256;
            int r = q >> 5, k4 = (q & 31) * 4;
            float4 v = src[q];
            u32 h0 = pkbf(v.x, v.y), h1 = pkbf(v.z, v.w);
            u32* hd = (u32*)&s_ahi[r * PAD128 + k4];
            hd[0] = h0; hd[1] = h1;
            if (SPLIT) {
                u32 l0 = pkbf(v.x - bf2f((u16)h0), v.y - bf2f((u16)(h0 >> 16)));
                u32 l1 = pkbf(v.z - bf2f((u16)h1), v.w - bf2f((u16)(h1 >> 16)));
                u32* ld = (u32*)&s_alo[r * PAD128 + k4];
                ld[0] = l0; ld[1] = l1;
            }
        }
    }
    {
        const uint4* src = (const uint4*)Bt;
        for (int p = 0; p < 8; ++p) {
            int q = tid + p * 256;
            int r = q >> 4, c8 = (q & 15) * 8;
            *(uint4*)&s_b[r * PAD128 + c8] = src[q];
        }
    }
    if (tid < 128) s_bias[tid] = bias[tid];
    __syncthreads();

    int wv = tid >> 6, lane = tid & 63;
    int quad = lane >> 4, lr = lane & 15;
    int n0 = wv * 32;
    f32x4 acc[2][2];
#pragma unroll
    for (int mt = 0; mt < 2; ++mt)
#pragma unroll
        for (int nt = 0; nt < 2; ++nt) acc[mt][nt] = (f32x4){0.f, 0.f, 0.f, 0.f};
#pragma unroll
    for (int kk = 0; kk < 128; kk += 32) {
        bf16x8 ah0 = ldfrag(&s_ahi[(lr)      * PAD128 + kk + quad * 8]);
        bf16x8 ah1 = ldfrag(&s_ahi[(16 + lr) * PAD128 + kk + quad * 8]);
#pragma unroll
        for (int nt = 0; nt < 2; ++nt) {
            bf16x8 b = ldfrag(&s_b[(n0 + nt * 16 + lr) * PAD128 + kk + quad * 8]);
            acc[0][nt] = __builtin_amdgcn_mfma_f32_16x16x32_bf16(ah0, b, acc[0][nt], 0, 0, 0);
            acc[1][nt] = __builtin_amdgcn_mfma_f32_16x16x32_bf16(ah1, b, acc[1][nt], 0, 0, 0);
        }
        if (SPLIT) {
            bf16x8 al0 = ldfrag(&s_alo[(lr)      * PAD128 + kk + quad * 8]);
            bf16x8 al1 = ldfrag(&s_alo[(16 + lr) * PAD128 + kk + quad * 8]);
#pragma unroll
            for (int nt = 0; nt < 2; ++nt) {
                bf16x8 b = ldfrag(&s_b[(n0 + nt * 16 + lr) * PAD128 + kk + quad * 8]);
                acc[0][nt] = __builtin_amdgcn_mfma_f32_16x16x32_bf16(al0, b, acc[0][nt], 0, 0, 0);
                acc[1][nt] = __builtin_amdgcn_mfma_f32_16x16x32_bf16(al1, b, acc[1][nt], 0, 0, 0);
            }
        }
    }
#pragma unroll
    for (int mt = 0; mt < 2; ++mt)
#pragma unroll
        for (int nt = 0; nt < 2; ++nt)
#pragma unroll
            for (int r = 0; r < 4; ++r) {
                int grow = row0 + mt * 16 + quad * 4 + r;
                int col = n0 + nt * 16 + lr;
                float v = acc[mt][nt][r] + s_bias[col];
                size_t off = (size_t)grow * 128 + col;
                if (MODE == 0) O[off] = v;
                else           O[off] += silu_f(v);
            }
}

// ---------------------------------------------------------------------------
// K4a: filter tables for ALL layers (runs once). Vtmp[l][t][c] = cv(d_t) *
// (silu(rbf(d_t)@mw1_l+b1_l)@mw2_l+b2_l)[c]. Full fp32.
// ---------------------------------------------------------------------------
__launch_bounds__(256)
__global__ void vtab_kernel(const float* __restrict__ mw1f,   // [6][50][128]
                            const float* __restrict__ mw2f,   // [6][128][128]
                            const float* __restrict__ b1,     // [6][128]
                            const float* __restrict__ b2,     // [6][128]
                            float* __restrict__ Vtmp) {       // [6][NTAB][128]
    __shared__ float s_rbf[2][64];
    __shared__ float s_t1[2][128];
    int tid = threadIdx.x;
    int rw = tid >> 7, col = tid & 127;
    int l = blockIdx.x / (NTAB / 2);
    int row = (blockIdx.x % (NTAB / 2)) * 2 + rw;
    const float* w1 = mw1f + (size_t)l * 6400;
    const float* w2 = mw2f + (size_t)l * 16384;
    float d = (float)row * (10.0f / (float)(NTAB - 1));
    if (col < NGAUSS) {
        float tt = (d - (10.0f / 49.0f) * (float)col) * (49.0f / 10.0f);
        s_rbf[rw][col] = __expf(-0.5f * tt * tt);
    }
    __syncthreads();
    float a = b1[l * 128 + col];
#pragma unroll 10
    for (int g = 0; g < NGAUSS; ++g) a += s_rbf[rw][g] * w1[g * 128 + col];
    s_t1[rw][col] = silu_f(a);
    __syncthreads();
    float v = b2[l * 128 + col];
#pragma unroll 8
    for (int f = 0; f < 128; ++f) v += s_t1[rw][f] * w2[f * 128 + col];
    float cv = 0.5f * (cosf(d * 3.14159265f / 10.0f) + 1.0f);
    Vtmp[((size_t)l * NTAB + row) * 128 + col] = v * cv;
}

// ---------------------------------------------------------------------------
// K4b: pack tables as (V0,V1,D0,D1) float4 per feature-pair: one 16B load
// per edge per lane in agg instead of two 8B loads.
// ---------------------------------------------------------------------------
__global__ void pack_vtab(const float* __restrict__ Vtmp, float4* __restrict__ pk) {
    int gid = blockIdx.x * 256 + threadIdx.x;
    if (gid >= LAYERS * NTAB * 64) return;
    int c = gid & 63;
    int row = (gid >> 6) & (NTAB - 1);
    int l = gid >> 17;                       // NTAB*64 = 2^17
    const float* vr = Vtmp + ((size_t)l * NTAB + row) * 128;
    const float* vn = (row < NTAB - 1) ? vr + 128 : vr;
    float v0 = vr[2 * c], v1 = vr[2 * c + 1];
    pk[gid] = make_float4(v0, v1, vn[2 * c] - v0, vn[2 * c + 1] - v1);
}

// ---------------------------------------------------------------------------
// K4c: aggregate. One wave per receiver: agg[j] = sum_e lerp(pk,d_e)*xj[src].
// 2 loads/edge (packed V+D float4, xj float2), unroll x4. No atomics.
// ---------------------------------------------------------------------------
__launch_bounds__(256)
__global__ void agg_kernel(const int* __restrict__ rev_cnt,
                           const int2* __restrict__ rev_si,
                           const float* __restrict__ rev_fr,
                           const float4* __restrict__ pk,
                           const float* __restrict__ xj,
                           float* __restrict__ agg) {
    int j = blockIdx.x * 4 + (threadIdx.x >> 6);
    int lane = threadIdx.x & 63;
    int deg = rev_cnt[j];
    const int2*  si = rev_si + (size_t)j * 128;
    const float* fr = rev_fr + (size_t)j * 128;
    int c2 = lane * 2;
    float a0 = 0.f, a1 = 0.f, b0 = 0.f, b1 = 0.f;
    float c0 = 0.f, c1 = 0.f, d0 = 0.f, d1 = 0.f;
    int it = 0;
    for (; it + 4 <= deg; it += 4) {
        int2 s0 = si[it], s1 = si[it + 1], s2 = si[it + 2], s3 = si[it + 3];
        float f0 = fr[it], f1 = fr[it + 1], f2 = fr[it + 2], f3 = fr[it + 3];
        float4 t0 = pk[(size_t)s0.y * 64 + lane];
        float4 t1 = pk[(size_t)s1.y * 64 + lane];
        float4 t2 = pk[(size_t)s2.y * 64 + lane];
        float4 t3 = pk[(size_t)s3.y * 64 + lane];
        float2 x0 = *(const float2*)(xj + (size_t)s0.x * 128 + c2);
        float2 x1 = *(const float2*)(xj + (size_t)s1.x * 128 + c2);
        float2 x2 = *(const float2*)(xj + (size_t)s2.x * 128 + c2);
        float2 x3 = *(const float2*)(xj + (size_t)s3.x * 128 + c2);
        a0 += (t0.x + t0.z * f0) * x0.x;  a1 += (t0.y + t0.w * f0) * x0.y;
        b0 += (t1.x + t1.z * f1) * x1.x;  b1 += (t1.y + t1.w * f1) * x1.y;
        c0 += (t2.x + t2.z * f2) * x2.x;  c1 += (t2.y + t2.w * f2) * x2.y;
        d0 += (t3.x + t3.z * f3) * x3.x;  d1 += (t3.y + t3.w * f3) * x3.y;
    }
    for (; it < deg; ++it) {
        int2 s0 = si[it];
        float f0 = fr[it];
        float4 t0 = pk[(size_t)s0.y * 64 + lane];
        float2 x0 = *(const float2*)(xj + (size_t)s0.x * 128 + c2);
        a0 += (t0.x + t0.z * f0) * x0.x;
        a1 += (t0.y + t0.w * f0) * x0.y;
    }
    float2 r;
    r.x = (a0 + b0) + (c0 + d0);
    r.y = (a1 + b1) + (c1 + d1);
    *(float2*)(agg + (size_t)j * 128 + c2) = r;
}

// ---------------------------------------------------------------------------
// K6: output head — 16 atoms/block, LDS-tiled, one atomic per block.
// ---------------------------------------------------------------------------
__launch_bounds__(256)
__global__ void head_kernel(const float* __restrict__ h,
                            const float* __restrict__ ow1,
                            const float* __restrict__ ob1,
                            const float* __restrict__ ow2,
                            const float* __restrict__ ob2,
                            float* __restrict__ gsum) {
    __shared__ __align__(16) float s_w[128 * 64];
    __shared__ __align__(16) float s_h[16 * 132];
    __shared__ float s_sum;
    int tid = threadIdx.x;
    int a0 = blockIdx.x * 16;
    if (tid == 0) s_sum = 0.0f;
    {
        const float4* src = (const float4*)ow1;
        float4* dst = (float4*)s_w;
#pragma unroll
        for (int p = 0; p < 8; ++p) dst[tid + p * 256] = src[tid + p * 256];
    }
    {
        const float4* src = (const float4*)(h + (size_t)a0 * 128);
#pragma unroll
        for (int p = 0; p < 2; ++p) {
            int q = tid + p * 256;
            int r = q >> 5, c4 = (q & 31) * 4;
            *(float4*)&s_h[r * 132 + c4] = src[q];
        }
    }
    __syncthreads();
    int atom = tid >> 4, cg = tid & 15;
    const float* hr = &s_h[atom * 132];
    const float4* w4 = (const float4*)s_w;
    float4 acc = {0.f, 0.f, 0.f, 0.f};
#pragma unroll 8
    for (int f = 0; f < 128; ++f) {
        float hv = hr[f];
        float4 w = w4[f * 16 + cg];
        acc.x += hv * w.x; acc.y += hv * w.y;
        acc.z += hv * w.z; acc.w += hv * w.w;
    }
    int c0 = cg * 4;
    float v = silu_f(acc.x + ob1[c0 + 0]) * ow2[c0 + 0]
            + silu_f(acc.y + ob1[c0 + 1]) * ow2[c0 + 1]
            + silu_f(acc.z + ob1[c0 + 2]) * ow2[c0 + 2]
            + silu_f(acc.w + ob1[c0 + 3]) * ow2[c0 + 3];
    v += __shfl_xor(v, 1, 64);
    v += __shfl_xor(v, 2, 64);
    v += __shfl_xor(v, 4, 64);
    v += __shfl_xor(v, 8, 64);
    if ((tid & 15) == 0) atomicAdd(&s_sum, v + ob2[0]);
    __syncthreads();
    if (tid == 0) atomicAdd(&gsum[a0 >> 7], s_sum);
}

__global__ void finalize_kernel(const float* __restrict__ gsum, void* __restrict__ out,
                                const int* __restrict__ flag) {
    int t = threadIdx.x;
    if (*flag) ((float*)out)[t] = gsum[t];
    else       ((u16*)out)[t]   = f2bf(gsum[t]);
}

// ---------------------------------------------------------------------------
extern "C" void kernel_launch(void* const* d_in, const int* in_sizes, int n_in,
                              void* d_out, int out_size, void* d_ws, size_t ws_size,
                              hipStream_t stream) {
    const void* pos  = d_in[0];
    const int*  z    = (const int*)d_in[1];
    // d_in[2] = batch (implicit: graph = i >> 7)
    const void* emb  = d_in[3];
    const void* mw1  = d_in[4];
    const void* mb1  = d_in[5];
    const void* mw2  = d_in[6];
    const void* mb2  = d_in[7];
    const void* l1w  = d_in[8];
    const void* l1b  = d_in[9];
    const void* l2w  = d_in[10];
    const void* l2b  = d_in[11];
    const void* ow1  = d_in[12];
    const void* ob1  = d_in[13];
    const void* ow2  = d_in[14];
    const void* ob2  = d_in[15];

    char* ws = (char*)d_ws;
    const size_t KB = 1024, MB = 1048576;
    int*   w_flag  = (int*)  (ws);
    float* c_pos   = (float*)(ws + 4   * KB);
    float* c_emb   = (float*)(ws + 112 * KB);
    float* c_mb1   = (float*)(ws + 168 * KB);
    float* c_mb2   = (float*)(ws + 176 * KB);
    float* c_l1b   = (float*)(ws + 184 * KB);
    float* c_l2b   = (float*)(ws + 192 * KB);
    float* c_ow1   = (float*)(ws + 200 * KB);
    float* c_ob1   = (float*)(ws + 236 * KB);
    float* c_ow2   = (float*)(ws + 240 * KB);
    float* c_ob2   = (float*)(ws + 244 * KB);
    float* w_gsum  = (float*)(ws + 248 * KB);
    u16*   c_l1wt  = (u16*)  (ws + 256 * KB);   // 192 KB
    u16*   c_l2wt  = (u16*)  (ws + 448 * KB);   // 192 KB
    float* c_mw1f  = (float*)(ws + 640 * KB);   // 150 KB fp32
    float* c_mw2f  = (float*)(ws + 800 * KB);   // 384 KB fp32
    float* w_dist  = (float*)(ws + 2  * MB);    // 1 MB
    int*   rev_cnt = (int*)  (ws + 4  * MB);    // 32 KB
    int*   rev_e   = (int*)  (ws + 5  * MB);    // 4 MB
    float* w_h     = (float*)(ws + 9  * MB);
    float* w_xj    = (float*)(ws + 13 * MB);
    float* w_agg   = (float*)(ws + 17 * MB);
    float* w_vtmp  = (float*)(ws + 21 * MB);    // 6 MB
    float4* w_pk   = (float4*)(ws + 27 * MB);   // 12 MB
    int2*  rev_si  = (int2*) (ws + 39 * MB);    // 8 MB
    float* rev_fr  = (float*)(ws + 47 * MB);    // 4 MB

    hipMemsetAsync(rev_cnt, 0, NATOMS * sizeof(int), stream);
    hipMemsetAsync(w_gsum, 0, GRAPHS * sizeof(float), stream);

    probe_kernel<<<1, 256, 0, stream>>>((const u16*)emb, w_flag);

    IngestDesc dsc;
    const void* srcs[NARR] = {pos, emb, mb1, mb2, l1b, l2b, ow1, ob1, ow2, ob2,
                              mw1, mw2};
    void* dsts[NARR] = {c_pos, c_emb, c_mb1, c_mb2, c_l1b, c_l2b, c_ow1, c_ob1,
                        c_ow2, c_ob2, c_mw1f, c_mw2f};
    int ns_[NARR] = {24576, 12800, 768, 768, 768, 768, 8192, 64, 64, 1,
                     38400, 98304};
    int total = 0;
    for (int a = 0; a < NARR; ++a) {
        dsc.src[a] = srcs[a]; dsc.dst[a] = dsts[a]; dsc.n[a] = ns_[a];
        total += ns_[a];
    }
    ingest_kernel<<<(total + 255) / 256, 256, 0, stream>>>(dsc, w_flag, total);
    prep_weights<<<768, 256, 0, stream>>>(l1w, l2w, c_l1wt, c_l2wt, w_flag);

    build_graph_kernel<<<NATOMS / 4, 256, 0, stream>>>(c_pos, w_dist,
                                                       rev_cnt, rev_e);
    edge_prep<<<NATOMS * 128 / 256, 256, 0, stream>>>(rev_cnt, rev_e, w_dist,
                                                      rev_si, rev_fr);
    embed_kernel<<<NATOMS, HID, 0, stream>>>(z, c_emb, w_h);

    // all-layer filter tables, once
    vtab_kernel<<<LAYERS * NTAB / 2, 256, 0, stream>>>(
        c_mw1f, c_mw2f, c_mb1, c_mb2, w_vtmp);
    pack_vtab<<<(LAYERS * NTAB * 64 + 255) / 256, 256, 0, stream>>>(w_vtmp, w_pk);

    for (int l = 0; l < LAYERS; ++l) {
        gemm_mfma<0, 0><<<NATOMS / 32, 256, 0, stream>>>(
            w_h, c_l1wt + (size_t)l * 16384, c_l1b + (size_t)l * 128, w_xj);
        agg_kernel<<<NATOMS / 4, 256, 0, stream>>>(
            rev_cnt, rev_si, rev_fr, w_pk + (size_t)l * NTAB * 64, w_xj, w_agg);
        gemm_mfma<1, 1><<<NATOMS / 32, 256, 0, stream>>>(
            w_agg, c_l2wt + (size_t)l * 16384, c_l2b + (size_t)l * 128, w_h);
    }

    head_kernel<<<NATOMS / 16, 256, 0, stream>>>(w_h, c_ow1, c_ob1, c_ow2, c_ob2,
                                                 w_gsum);
    finalize_kernel<<<1, GRAPHS, 0, stream>>>(w_gsum, (void*)d_out, w_flag);
}

// Round 11
// 359.475 us; speedup vs baseline: 2.7246x; 1.1167x over previous
//
#include <hip/hip_runtime.h>
#include <math.h>

typedef unsigned short u16;
typedef unsigned int   u32;
typedef unsigned long long u64;

#define NATOMS 8192
#define GRAPHS 64
#define APG    128
#define KNN    32
#define NGAUSS 50
#define HID    128
#define LAYERS 6
#define PAD128 136
#define NTAB   2048

typedef __attribute__((ext_vector_type(8))) short bf16x8;
typedef __attribute__((ext_vector_type(4))) float f32x4;

__device__ __forceinline__ float bf2f(u16 v) {
    return __uint_as_float(((u32)v) << 16);
}
__device__ __forceinline__ u16 f2bf(float f) {
    u32 u = __float_as_uint(f);
    u32 lsb = (u >> 16) & 1u;
    u += 0x7fffu + lsb;
    return (u16)(u >> 16);
}
__device__ __forceinline__ u32 pkbf(float lo, float hi) {
#if __has_builtin(__builtin_amdgcn_cvt_pk_bf16_f32)
    auto r = __builtin_amdgcn_cvt_pk_bf16_f32(lo, hi);
    u32 u; __builtin_memcpy(&u, &r, 4); return u;
#else
    return (u32)f2bf(lo) | ((u32)f2bf(hi) << 16);
#endif
}
__device__ __forceinline__ float silu_f(float x) {
    return x * __builtin_amdgcn_rcpf(1.0f + __expf(-x));
}
__device__ __forceinline__ bf16x8 ldfrag(const u16* p) {
    return *(const bf16x8*)__builtin_assume_aligned(p, 16);
}
__device__ __forceinline__ u64 shfl_xor_u64(u64 v, int mask) {
    u32 lo = (u32)v, hi = (u32)(v >> 32);
    lo = (u32)__shfl_xor((int)lo, mask, 64);
    hi = (u32)__shfl_xor((int)hi, mask, 64);
    return ((u64)hi << 32) | lo;
}

// ---------------------------------------------------------------------------
// K0: dtype probe (fp32 vs bf16 float inputs)
// ---------------------------------------------------------------------------
__global__ void probe_kernel(const u16* __restrict__ raw, int* __restrict__ flag) {
    __shared__ int s;
    int t = threadIdx.x;
    if (t == 0) s = 0;
    __syncthreads();
    float x = bf2f(raw[2 * t]);
    if (!(fabsf(x) < 1000.0f)) atomicOr(&s, 1);
    __syncthreads();
    if (t == 0) *flag = s;
}

// ---------------------------------------------------------------------------
// K0b: ingest fp32-canonical copies (incl. mw1/mw2 full fp32 for the table).
// ---------------------------------------------------------------------------
#define NARR 12
struct IngestDesc {
    const void* src[NARR];
    void*       dst[NARR];
    int         n[NARR];
};

__global__ void ingest_kernel(IngestDesc d, const int* __restrict__ flag, int total) {
    int gid = blockIdx.x * blockDim.x + threadIdx.x;
    if (gid >= total) return;
    int a = 0, off = gid;
    while (off >= d.n[a]) { off -= d.n[a]; ++a; }
    bool f32in = (*flag != 0);
    float v = f32in ? ((const float*)d.src[a])[off]
                    : bf2f(((const u16*)d.src[a])[off]);
    ((float*)d.dst[a])[off] = v;
}

// ---------------------------------------------------------------------------
// K0c: weight prep — transpose l1w/l2w to [n][k] bf16 for MFMA B-operands.
// ---------------------------------------------------------------------------
__global__ void prep_weights(const void* __restrict__ l1w, const void* __restrict__ l2w,
                             u16* __restrict__ l1wt, u16* __restrict__ l2wt,
                             const int* __restrict__ flag) {
    int gid = blockIdx.x * blockDim.x + threadIdx.x;
    if (gid >= 2 * 98304) return;
    bool f32in = (*flag != 0);
    int seg = gid / 98304;
    int t = gid % 98304;
    int l = t >> 14;
    int n = (t >> 7) & 127;
    int k = t & 127;
    const void* src = (seg == 0) ? l1w : l2w;
    u16* dst = (seg == 0) ? l1wt : l2wt;
    int si = l * 16384 + k * 128 + n;
    float v = f32in ? ((const float*)src)[si] : bf2f(((const u16*)src)[si]);
    dst[t] = f2bf(v);
}

// ---------------------------------------------------------------------------
// K1: graph build + edge prep fused. One WAVE per center atom; full bitonic
// sort of 128 (d2,j) u64 keys (verified R10). Valid edges (d<10) are pushed
// into receiver lists directly as (src=center, table idx, frac).
// ---------------------------------------------------------------------------
__launch_bounds__(256)
__global__ void build_graph_kernel(const float* __restrict__ pos,
                                   int* __restrict__ rev_cnt,
                                   int2* __restrict__ rev_si,
                                   float* __restrict__ rev_fr) {
    int wv = threadIdx.x >> 6, lane = threadIdx.x & 63;
    int t = blockIdx.x * 4 + wv;
    int tl = t & 127;
    int base = t & ~127;
    float cx = pos[t * 3 + 0];
    float cy = pos[t * 3 + 1];
    float cz = pos[t * 3 + 2];
    u64 key[2];
#pragma unroll
    for (int c = 0; c < 2; ++c) {
        int j = lane + c * 64;
        float jx = pos[(base + j) * 3 + 0];
        float jy = pos[(base + j) * 3 + 1];
        float jz = pos[(base + j) * 3 + 2];
        float dx = __fsub_rn(cx, jx);
        float dy = __fsub_rn(cy, jy);
        float dz = __fsub_rn(cz, jz);
        float d2 = __fadd_rn(__fadd_rn(__fmul_rn(dx, dx), __fmul_rn(dy, dy)),
                             __fmul_rn(dz, dz));
        bool valid = (j != tl) && (d2 < 100.0f);
        key[c] = valid ? ((((u64)__float_as_uint(d2)) << 32) | (u32)j) : ~0ULL;
    }
    // bitonic sort, element index ii = reg*64 + lane, ascending
#pragma unroll
    for (int k = 2; k <= 128; k <<= 1) {
#pragma unroll
        for (int j = k >> 1; j > 0; j >>= 1) {
            if (j == 64) {
                u64 lo = key[0] < key[1] ? key[0] : key[1];
                u64 hi = key[0] < key[1] ? key[1] : key[0];
                key[0] = lo; key[1] = hi;
            } else {
#pragma unroll
                for (int r = 0; r < 2; ++r) {
                    u64 o = shfl_xor_u64(key[r], j);
                    u32 ii = (u32)(r * 64 + lane);
                    bool dir = ((ii & (u32)k) == 0);
                    bool lower = ((ii & (u32)j) == 0);
                    bool keep_min = (dir == lower);
                    bool less = key[r] < o;
                    key[r] = (less == keep_min) ? key[r] : o;
                }
            }
        }
    }
    if (lane < KNN) {
        u64 m = key[0];
        if (m != ~0ULL) {
            float d2 = __uint_as_float((u32)(m >> 32));
            float d = __fsqrt_rn(d2);
            if (d < 10.0f) {
                float u = d * ((float)(NTAB - 1) / 10.0f);
                int i0 = (int)u;
                if (i0 > NTAB - 2) i0 = NTAB - 2;
                int jn = base + (int)(m & 0xffffffffu);
                int p = atomicAdd(&rev_cnt[jn], 1);
                rev_si[(size_t)jn * 128 + p] = make_int2(t, i0);
                rev_fr[(size_t)jn * 128 + p] = u - (float)i0;
            }
        }
    }
}

// ---------------------------------------------------------------------------
// K2: embedding gather
// ---------------------------------------------------------------------------
__global__ void embed_kernel(const int* __restrict__ z,
                             const float* __restrict__ emb,
                             float* __restrict__ h) {
    int i = blockIdx.x, t = threadIdx.x;
    h[(size_t)i * HID + t] = emb[(size_t)z[i] * HID + t];
}

// ---------------------------------------------------------------------------
// K3: dense MFMA GEMM, 16 rows/block (512 blocks -> 2-3 blocks/CU).
// SPLIT=1: A as hi+lo bf16 (h path). OUT16=1: write bf16 (xj path).
// MODE 0: O = res; MODE 1: O += silu(res).
// ---------------------------------------------------------------------------
template <int MODE, int SPLIT, int OUT16>
__launch_bounds__(256)
__global__ void gemm_mfma(const float* __restrict__ A,
                          const u16* __restrict__ Bt,
                          const float* __restrict__ bias,
                          void* __restrict__ O) {
    __shared__ u16 s_ahi[16 * PAD128];
    __shared__ u16 s_alo[SPLIT ? 16 * PAD128 : 2];
    __shared__ u16 s_b[128 * PAD128];
    __shared__ float s_bias[128];
    int tid = threadIdx.x;
    int row0 = blockIdx.x * 16;
    {
        const float4* src = (const float4*)(A + (size_t)row0 * 128);
        for (int p = 0; p < 2; ++p) {
            int q = tid + p * 256;
            int r = q >> 5, k4 = (q & 31) * 4;
            float4 v = src[q];
            u32 h0 = pkbf(v.x, v.y), h1 = pkbf(v.z, v.w);
            u32* hd = (u32*)&s_ahi[r * PAD128 + k4];
            hd[0] = h0; hd[1] = h1;
            if (SPLIT) {
                u32 l0 = pkbf(v.x - bf2f((u16)h0), v.y - bf2f((u16)(h0 >> 16)));
                u32 l1 = pkbf(v.z - bf2f((u16)h1), v.w - bf2f((u16)(h1 >> 16)));
                u32* ld = (u32*)&s_alo[r * PAD128 + k4];
                ld[0] = l0; ld[1] = l1;
            }
        }
    }
    {
        const uint4* src = (const uint4*)Bt;
        for (int p = 0; p < 8; ++p) {
            int q = tid + p * 256;
            int r = q >> 4, c8 = (q & 15) * 8;
            *(uint4*)&s_b[r * PAD128 + c8] = src[q];
        }
    }
    if (tid < 128) s_bias[tid] = bias[tid];
    __syncthreads();

    int wv = tid >> 6, lane = tid & 63;
    int quad = lane >> 4, lr = lane & 15;
    int n0 = wv * 32;
    f32x4 acc[2];
#pragma unroll
    for (int nt = 0; nt < 2; ++nt) acc[nt] = (f32x4){0.f, 0.f, 0.f, 0.f};
#pragma unroll
    for (int kk = 0; kk < 128; kk += 32) {
        bf16x8 ah = ldfrag(&s_ahi[lr * PAD128 + kk + quad * 8]);
#pragma unroll
        for (int nt = 0; nt < 2; ++nt) {
            bf16x8 b = ldfrag(&s_b[(n0 + nt * 16 + lr) * PAD128 + kk + quad * 8]);
            acc[nt] = __builtin_amdgcn_mfma_f32_16x16x32_bf16(ah, b, acc[nt], 0, 0, 0);
            if (SPLIT) {
                bf16x8 al = ldfrag(&s_alo[lr * PAD128 + kk + quad * 8]);
                acc[nt] = __builtin_amdgcn_mfma_f32_16x16x32_bf16(al, b, acc[nt], 0, 0, 0);
            }
        }
    }
#pragma unroll
    for (int nt = 0; nt < 2; ++nt)
#pragma unroll
        for (int r = 0; r < 4; ++r) {
            int grow = row0 + quad * 4 + r;
            int col = n0 + nt * 16 + lr;
            float v = acc[nt][r] + s_bias[col];
            size_t off = (size_t)grow * 128 + col;
            if (OUT16)          ((u16*)O)[off] = f2bf(v);
            else if (MODE == 0) ((float*)O)[off] = v;
            else                ((float*)O)[off] += silu_f(v);
        }
}

// ---------------------------------------------------------------------------
// K4a: filter tables for ALL layers (runs once). Full fp32.
// ---------------------------------------------------------------------------
__launch_bounds__(256)
__global__ void vtab_kernel(const float* __restrict__ mw1f,   // [6][50][128]
                            const float* __restrict__ mw2f,   // [6][128][128]
                            const float* __restrict__ b1,     // [6][128]
                            const float* __restrict__ b2,     // [6][128]
                            float* __restrict__ Vtmp) {       // [6][NTAB][128]
    __shared__ float s_rbf[2][64];
    __shared__ float s_t1[2][128];
    int tid = threadIdx.x;
    int rw = tid >> 7, col = tid & 127;
    int l = blockIdx.x / (NTAB / 2);
    int row = (blockIdx.x % (NTAB / 2)) * 2 + rw;
    const float* w1 = mw1f + (size_t)l * 6400;
    const float* w2 = mw2f + (size_t)l * 16384;
    float d = (float)row * (10.0f / (float)(NTAB - 1));
    if (col < NGAUSS) {
        float tt = (d - (10.0f / 49.0f) * (float)col) * (49.0f / 10.0f);
        s_rbf[rw][col] = __expf(-0.5f * tt * tt);
    }
    __syncthreads();
    float a = b1[l * 128 + col];
#pragma unroll 10
    for (int g = 0; g < NGAUSS; ++g) a += s_rbf[rw][g] * w1[g * 128 + col];
    s_t1[rw][col] = silu_f(a);
    __syncthreads();
    float v = b2[l * 128 + col];
#pragma unroll 8
    for (int f = 0; f < 128; ++f) v += s_t1[rw][f] * w2[f * 128 + col];
    float cv = 0.5f * (cosf(d * 3.14159265f / 10.0f) + 1.0f);
    Vtmp[((size_t)l * NTAB + row) * 128 + col] = v * cv;
}

// ---------------------------------------------------------------------------
// K4b: pack tables as bf16 (V0,V1,D0,D1) ushort4 — 8B per edge per lane.
// ---------------------------------------------------------------------------
__global__ void pack_vtab(const float* __restrict__ Vtmp, ushort4* __restrict__ pk) {
    int gid = blockIdx.x * 256 + threadIdx.x;
    if (gid >= LAYERS * NTAB * 64) return;
    int c = gid & 63;
    int row = (gid >> 6) & (NTAB - 1);
    int l = gid >> 17;                       // NTAB*64 = 2^17
    const float* vr = Vtmp + ((size_t)l * NTAB + row) * 128;
    const float* vn = (row < NTAB - 1) ? vr + 128 : vr;
    float v0 = vr[2 * c], v1 = vr[2 * c + 1];
    ushort4 o;
    o.x = f2bf(v0); o.y = f2bf(v1);
    o.z = f2bf(vn[2 * c] - v0); o.w = f2bf(vn[2 * c + 1] - v1);
    pk[gid] = o;
}

// ---------------------------------------------------------------------------
// K4c: aggregate. One wave per receiver: agg[j] = sum_e lerp(pk,d_e)*xj[src].
// bf16 table (8B) + bf16 xj (4B) per edge per lane; fp32 accumulate.
// ---------------------------------------------------------------------------
__launch_bounds__(256)
__global__ void agg_kernel(const int* __restrict__ rev_cnt,
                           const int2* __restrict__ rev_si,
                           const float* __restrict__ rev_fr,
                           const ushort4* __restrict__ pk,
                           const u16* __restrict__ xjb,
                           float* __restrict__ agg) {
    int j = blockIdx.x * 4 + (threadIdx.x >> 6);
    int lane = threadIdx.x & 63;
    int deg = rev_cnt[j];
    const int2*  si = rev_si + (size_t)j * 128;
    const float* fr = rev_fr + (size_t)j * 128;
    int c2 = lane * 2;
    float a0 = 0.f, a1 = 0.f, b0 = 0.f, b1 = 0.f;
    float c0 = 0.f, c1 = 0.f, d0 = 0.f, d1 = 0.f;
    int it = 0;
    for (; it + 4 <= deg; it += 4) {
        int2 s0 = si[it], s1 = si[it + 1], s2 = si[it + 2], s3 = si[it + 3];
        float f0 = fr[it], f1 = fr[it + 1], f2 = fr[it + 2], f3 = fr[it + 3];
        ushort4 t0 = pk[(size_t)s0.y * 64 + lane];
        ushort4 t1 = pk[(size_t)s1.y * 64 + lane];
        ushort4 t2 = pk[(size_t)s2.y * 64 + lane];
        ushort4 t3 = pk[(size_t)s3.y * 64 + lane];
        ushort2 x0 = *(const ushort2*)(xjb + (size_t)s0.x * 128 + c2);
        ushort2 x1 = *(const ushort2*)(xjb + (size_t)s1.x * 128 + c2);
        ushort2 x2 = *(const ushort2*)(xjb + (size_t)s2.x * 128 + c2);
        ushort2 x3 = *(const ushort2*)(xjb + (size_t)s3.x * 128 + c2);
        a0 += (bf2f(t0.x) + bf2f(t0.z) * f0) * bf2f(x0.x);
        a1 += (bf2f(t0.y) + bf2f(t0.w) * f0) * bf2f(x0.y);
        b0 += (bf2f(t1.x) + bf2f(t1.z) * f1) * bf2f(x1.x);
        b1 += (bf2f(t1.y) + bf2f(t1.w) * f1) * bf2f(x1.y);
        c0 += (bf2f(t2.x) + bf2f(t2.z) * f2) * bf2f(x2.x);
        c1 += (bf2f(t2.y) + bf2f(t2.w) * f2) * bf2f(x2.y);
        d0 += (bf2f(t3.x) + bf2f(t3.z) * f3) * bf2f(x3.x);
        d1 += (bf2f(t3.y) + bf2f(t3.w) * f3) * bf2f(x3.y);
    }
    for (; it < deg; ++it) {
        int2 s0 = si[it];
        float f0 = fr[it];
        ushort4 t0 = pk[(size_t)s0.y * 64 + lane];
        ushort2 x0 = *(const ushort2*)(xjb + (size_t)s0.x * 128 + c2);
        a0 += (bf2f(t0.x) + bf2f(t0.z) * f0) * bf2f(x0.x);
        a1 += (bf2f(t0.y) + bf2f(t0.w) * f0) * bf2f(x0.y);
    }
    float2 r;
    r.x = (a0 + b0) + (c0 + d0);
    r.y = (a1 + b1) + (c1 + d1);
    *(float2*)(agg + (size_t)j * 128 + c2) = r;
}

// ---------------------------------------------------------------------------
// K6: output head — 16 atoms/block, LDS-tiled, one atomic per block.
// ---------------------------------------------------------------------------
__launch_bounds__(256)
__global__ void head_kernel(const float* __restrict__ h,
                            const float* __restrict__ ow1,
                            const float* __restrict__ ob1,
                            const float* __restrict__ ow2,
                            const float* __restrict__ ob2,
                            float* __restrict__ gsum) {
    __shared__ __align__(16) float s_w[128 * 64];
    __shared__ __align__(16) float s_h[16 * 132];
    __shared__ float s_sum;
    int tid = threadIdx.x;
    int a0 = blockIdx.x * 16;
    if (tid == 0) s_sum = 0.0f;
    {
        const float4* src = (const float4*)ow1;
        float4* dst = (float4*)s_w;
#pragma unroll
        for (int p = 0; p < 8; ++p) dst[tid + p * 256] = src[tid + p * 256];
    }
    {
        const float4* src = (const float4*)(h + (size_t)a0 * 128);
#pragma unroll
        for (int p = 0; p < 2; ++p) {
            int q = tid + p * 256;
            int r = q >> 5, c4 = (q & 31) * 4;
            *(float4*)&s_h[r * 132 + c4] = src[q];
        }
    }
    __syncthreads();
    int atom = tid >> 4, cg = tid & 15;
    const float* hr = &s_h[atom * 132];
    const float4* w4 = (const float4*)s_w;
    float4 acc = {0.f, 0.f, 0.f, 0.f};
#pragma unroll 8
    for (int f = 0; f < 128; ++f) {
        float hv = hr[f];
        float4 w = w4[f * 16 + cg];
        acc.x += hv * w.x; acc.y += hv * w.y;
        acc.z += hv * w.z; acc.w += hv * w.w;
    }
    int c0 = cg * 4;
    float v = silu_f(acc.x + ob1[c0 + 0]) * ow2[c0 + 0]
            + silu_f(acc.y + ob1[c0 + 1]) * ow2[c0 + 1]
            + silu_f(acc.z + ob1[c0 + 2]) * ow2[c0 + 2]
            + silu_f(acc.w + ob1[c0 + 3]) * ow2[c0 + 3];
    v += __shfl_xor(v, 1, 64);
    v += __shfl_xor(v, 2, 64);
    v += __shfl_xor(v, 4, 64);
    v += __shfl_xor(v, 8, 64);
    if ((tid & 15) == 0) atomicAdd(&s_sum, v + ob2[0]);
    __syncthreads();
    if (tid == 0) atomicAdd(&gsum[a0 >> 7], s_sum);
}

__global__ void finalize_kernel(const float* __restrict__ gsum, void* __restrict__ out,
                                const int* __restrict__ flag) {
    int t = threadIdx.x;
    if (*flag) ((float*)out)[t] = gsum[t];
    else       ((u16*)out)[t]   = f2bf(gsum[t]);
}

// ---------------------------------------------------------------------------
extern "C" void kernel_launch(void* const* d_in, const int* in_sizes, int n_in,
                              void* d_out, int out_size, void* d_ws, size_t ws_size,
                              hipStream_t stream) {
    const void* pos  = d_in[0];
    const int*  z    = (const int*)d_in[1];
    // d_in[2] = batch (implicit: graph = i >> 7)
    const void* emb  = d_in[3];
    const void* mw1  = d_in[4];
    const void* mb1  = d_in[5];
    const void* mw2  = d_in[6];
    const void* mb2  = d_in[7];
    const void* l1w  = d_in[8];
    const void* l1b  = d_in[9];
    const void* l2w  = d_in[10];
    const void* l2b  = d_in[11];
    const void* ow1  = d_in[12];
    const void* ob1  = d_in[13];
    const void* ow2  = d_in[14];
    const void* ob2  = d_in[15];

    char* ws = (char*)d_ws;
    const size_t KB = 1024, MB = 1048576;
    int*   w_flag  = (int*)  (ws);
    float* c_pos   = (float*)(ws + 4   * KB);
    float* c_emb   = (float*)(ws + 112 * KB);
    float* c_mb1   = (float*)(ws + 168 * KB);
    float* c_mb2   = (float*)(ws + 176 * KB);
    float* c_l1b   = (float*)(ws + 184 * KB);
    float* c_l2b   = (float*)(ws + 192 * KB);
    float* c_ow1   = (float*)(ws + 200 * KB);
    float* c_ob1   = (float*)(ws + 236 * KB);
    float* c_ow2   = (float*)(ws + 240 * KB);
    float* c_ob2   = (float*)(ws + 244 * KB);
    float* w_gsum  = (float*)(ws + 248 * KB);
    u16*   c_l1wt  = (u16*)  (ws + 256 * KB);   // 192 KB
    u16*   c_l2wt  = (u16*)  (ws + 448 * KB);   // 192 KB
    float* c_mw1f  = (float*)(ws + 640 * KB);   // 150 KB fp32
    float* c_mw2f  = (float*)(ws + 800 * KB);   // 384 KB fp32
    int*   rev_cnt = (int*)  (ws + 2  * MB);    // 32 KB
    int2*  rev_si  = (int2*) (ws + 3  * MB);    // 8 MB
    float* rev_fr  = (float*)(ws + 11 * MB);    // 4 MB
    float* w_h     = (float*)(ws + 15 * MB);    // 4 MB
    u16*   w_xjb   = (u16*)  (ws + 19 * MB);    // 2 MB bf16
    float* w_agg   = (float*)(ws + 21 * MB);    // 4 MB
    float* w_vtmp  = (float*)(ws + 25 * MB);    // 6 MB
    ushort4* w_pk  = (ushort4*)(ws + 31 * MB);  // 6 MB
    // end ~37 MB

    hipMemsetAsync(rev_cnt, 0, NATOMS * sizeof(int), stream);
    hipMemsetAsync(w_gsum, 0, GRAPHS * sizeof(float), stream);

    probe_kernel<<<1, 256, 0, stream>>>((const u16*)emb, w_flag);

    IngestDesc dsc;
    const void* srcs[NARR] = {pos, emb, mb1, mb2, l1b, l2b, ow1, ob1, ow2, ob2,
                              mw1, mw2};
    void* dsts[NARR] = {c_pos, c_emb, c_mb1, c_mb2, c_l1b, c_l2b, c_ow1, c_ob1,
                        c_ow2, c_ob2, c_mw1f, c_mw2f};
    int ns_[NARR] = {24576, 12800, 768, 768, 768, 768, 8192, 64, 64, 1,
                     38400, 98304};
    int total = 0;
    for (int a = 0; a < NARR; ++a) {
        dsc.src[a] = srcs[a]; dsc.dst[a] = dsts[a]; dsc.n[a] = ns_[a];
        total += ns_[a];
    }
    ingest_kernel<<<(total + 255) / 256, 256, 0, stream>>>(dsc, w_flag, total);
    prep_weights<<<768, 256, 0, stream>>>(l1w, l2w, c_l1wt, c_l2wt, w_flag);

    build_graph_kernel<<<NATOMS / 4, 256, 0, stream>>>(c_pos, rev_cnt,
                                                       rev_si, rev_fr);
    embed_kernel<<<NATOMS, HID, 0, stream>>>(z, c_emb, w_h);

    // all-layer filter tables, once
    vtab_kernel<<<LAYERS * NTAB / 2, 256, 0, stream>>>(
        c_mw1f, c_mw2f, c_mb1, c_mb2, w_vtmp);
    pack_vtab<<<(LAYERS * NTAB * 64 + 255) / 256, 256, 0, stream>>>(w_vtmp, w_pk);

    for (int l = 0; l < LAYERS; ++l) {
        gemm_mfma<0, 0, 1><<<NATOMS / 16, 256, 0, stream>>>(
            w_h, c_l1wt + (size_t)l * 16384, c_l1b + (size_t)l * 128, w_xjb);
        agg_kernel<<<NATOMS / 4, 256, 0, stream>>>(
            rev_cnt, rev_si, rev_fr, w_pk + (size_t)l * NTAB * 64, w_xjb, w_agg);
        gemm_mfma<1, 1, 0><<<NATOMS / 16, 256, 0, stream>>>(
            w_agg, c_l2wt + (size_t)l * 16384, c_l2b + (size_t)l * 128, w_h);
    }

    head_kernel<<<NATOMS / 16, 256, 0, stream>>>(w_h, c_ow1, c_ob1, c_ow2, c_ob2,
                                                 w_gsum);
    finalize_kernel<<<1, GRAPHS, 0, stream>>>(w_gsum, (void*)d_out, w_flag);
}